// Round 5
// baseline (2002.292 us; speedup 1.0000x reference)
//
#include <hip/hip_runtime.h>
#include <cstddef>

#define R_ 0.70710678118654752f
#define NEG_ 0.2f
#define EPS_ 1e-5f

constexpr int F_ = 64, C3_ = 192, HH_ = 128, NPIX_ = 16384, B_ = 4, LAT_ = 512, HYP_ = 33024;
// intra-row offsets inside one sample's hypernet output
constexpr int OFFI_WIN = 0, OFFI_BIN = 12288, OFFI_WMID = 12352, OFFI_BMID = 16448,
              OFFI_WOUT = 16512, OFFI_BOUT = 20608, OFFI_WSH = 20672, OFFI_BSH = 32960;
// workspace layout (float offsets)
constexpr size_t OFF_HYP = 0;         // 132096
constexpr size_t OFF_ABIN = 132096;   // 256
constexpr size_t OFF_ABSH = 132352;   // 256
constexpr size_t OFF_CNT = 132608;    // 16 ints (spin counters), rest spare to 134143
constexpr size_t OFF_SRAW = 134144;   // 6144
constexpr size_t OFF_WFIN = 140288;   // 4*24576 ushort = 49152 floats (hi/lo frag pairs)
constexpr size_t OFF_WFSH = 189440;   // 49152
constexpr size_t OFF_WFMID = 238592;  // 4*8192 ushort = 16384 floats
constexpr size_t OFF_WFOUT = 254976;  // 16384
constexpr size_t OFF_CW1 = 271360;    // 73728 ushort = 36864 floats (conv1 frag pairs)
constexpr size_t OFF_CW2 = 308224;    // 36864
constexpr size_t OFF_CWIMG = 345088;  // 1728
constexpr size_t OFF_OUT = 346816;    // 4194304
constexpr size_t OFF_SOB = 4541120;   // 4*128*16384 packed-uint = 8388608 "floats"
constexpr size_t OFF_TMP = OFF_SOB;   // epilogue h (fp32, 4194304) aliases sob
// total = 12,929,728 floats = 51.7 MB (same as R4 — known to fit)

typedef short bf16x8 __attribute__((ext_vector_type(8)));
typedef float f32x4 __attribute__((ext_vector_type(4)));

// fp32 -> bf16 (RNE)
static __device__ __forceinline__ unsigned short f2b(float v) {
  unsigned u = __builtin_bit_cast(unsigned, v);
  u += 0x7fffu + ((u >> 16) & 1u);
  return (unsigned short)(u >> 16);
}
static __device__ __forceinline__ float b2f(unsigned short h) {
  return __builtin_bit_cast(float, ((unsigned)h) << 16);
}
static __device__ __forceinline__ void split2(float v, unsigned short& hi, unsigned short& lo) {
  hi = f2b(v);
  lo = f2b(v - b2f(hi));
}

// triple-MFMA split-bf16 product: acc += Ahi*Whi + Ahi*Wlo + Alo*Whi
#define MM3(acc, ahi, alo, whi, wlo)                                        \
  acc = __builtin_amdgcn_mfma_f32_16x16x32_bf16(ahi, whi, acc, 0, 0, 0);    \
  acc = __builtin_amdgcn_mfma_f32_16x16x32_bf16(ahi, wlo, acc, 0, 0, 0);    \
  acc = __builtin_amdgcn_mfma_f32_16x16x32_bf16(alo, whi, acc, 0, 0, 0);

// ---------------- hypernetwork GEMM ----------------------------------------------
__global__ __launch_bounds__(256) void hyper_gemm_kernel(
    const float* __restrict__ lat, const float* __restrict__ hw,
    const float* __restrict__ hb, float* __restrict__ hyp) {
  __shared__ float slat[B_ * LAT_];
  const int tid = threadIdx.x;
  for (int i = tid; i < B_ * LAT_; i += 256) slat[i] = lat[i];
  __syncthreads();
  const int wave = tid >> 6, lane = tid & 63;
  const int j = blockIdx.x * 4 + wave;
  if (j >= HYP_) return;
  const float* wr = hw + (size_t)j * LAT_;
  float a0 = 0.f, a1 = 0.f, a2 = 0.f, a3 = 0.f;
  for (int i = 0; i < LAT_; i += 64) {
    float w = wr[i + lane];
    a0 = __builtin_fmaf(w, slat[0 * LAT_ + i + lane], a0);
    a1 = __builtin_fmaf(w, slat[1 * LAT_ + i + lane], a1);
    a2 = __builtin_fmaf(w, slat[2 * LAT_ + i + lane], a2);
    a3 = __builtin_fmaf(w, slat[3 * LAT_ + i + lane], a3);
  }
  #pragma unroll
  for (int off = 32; off; off >>= 1) {
    a0 += __shfl_down(a0, off, 64);
    a1 += __shfl_down(a1, off, 64);
    a2 += __shfl_down(a2, off, 64);
    a3 += __shfl_down(a3, off, 64);
  }
  if (lane == 0) {
    float b = hb[j];
    hyp[0 * HYP_ + j] = a0 + b;
    hyp[1 * HYP_ + j] = a1 + b;
    hyp[2 * HYP_ + j] = a2 + b;
    hyp[3 * HYP_ + j] = a3 + b;
  }
}

// ---------------- conv weights -> split-bf16 frag layout (+ img transpose) --------
// wf[((ks*4+g)*64 + ch_out)*16 + j] = hi, [+8+j] = lo of W[ch_out][k], k = ks*32+g*8+j,
// tap-major: k = t*64 + c_in  (t = k>>6, c_in = k&63)
__global__ __launch_bounds__(256) void prep_convw_kernel(
    const float* __restrict__ w1, const float* __restrict__ w2,
    const float* __restrict__ wi, unsigned short* __restrict__ wf1,
    unsigned short* __restrict__ wf2, float* __restrict__ wit) {
  const int idx = blockIdx.x * 256 + threadIdx.x;
  if (idx < 36864) {
    int j = idx & 7, ch = (idx >> 3) & 63, fg = idx >> 9;  // fg = ks*4+g
    int k = (fg >> 2) * 32 + (fg & 3) * 8 + j;
    int c = k & 63, t = k >> 6;
    int fb = (fg * 64 + ch) * 16;
    unsigned short h, l;
    split2(w1[(ch * 64 + c) * 9 + t], h, l);
    wf1[fb + j] = h; wf1[fb + 8 + j] = l;
    split2(w2[(ch * 64 + c) * 9 + t], h, l);
    wf2[fb + j] = h; wf2[fb + 8 + j] = l;
  }
  if (idx < 64 * 9 * 3) {
    int k = idx % 3, rest = idx / 3;
    int t = rest % 9, c = rest / 9;
    wit[idx] = wi[(k * 64 + c) * 9 + t];
  }
}

// ---------------- block reduction helper ------------------------------------------
__device__ __forceinline__ float blockReduceSum(float v, float* scratch) {
  const int tid = threadIdx.x;
  #pragma unroll
  for (int off = 32; off; off >>= 1) v += __shfl_down(v, off, 64);
  if ((tid & 63) == 0) scratch[tid >> 6] = v;
  __syncthreads();
  float r = scratch[0] + scratch[1] + scratch[2] + scratch[3];
  __syncthreads();
  return r;
}

__device__ __forceinline__ void hline_z(const float* __restrict__ P, int rr, int col,
                                        float& hdv, float& hsv, float& cv) {
  if (rr < 0 || rr > 127) { hdv = 0.f; hsv = 0.f; cv = 0.f; return; }
  const float* rp = P + rr * HH_;
  float vm2 = (col >= 2) ? rp[col - 2] : 0.f;
  float vm1 = (col >= 1) ? rp[col - 1] : 0.f;
  float v0 = rp[col];
  float vp1 = (col <= 126) ? rp[col + 1] : 0.f;
  float vp2 = (col <= 125) ? rp[col + 2] : 0.f;
  hdv = -vm2 - R_ * vm1 + R_ * vp1 + vp2;
  hsv = R_ * vm1 + v0 + R_ * vp1;
  cv = v0;
}

// ---------------- fused: SinSobel + IN partials (1024 workers) + wadjust (32 spinners)
__global__ __launch_bounds__(256, 6) void sobel_wadj_kernel(float* wsm, int st) {
  __shared__ float scr[4];
  const int bi = blockIdx.x;
  const int tid = threadIdx.x;
  int* cnt = (int*)(wsm + OFF_CNT) + st;

  if (bi >= 1024) {
    // ---------- finalizer: wait for all workers, then fold IN into weights -------
    const int fb = bi - 1024;
    if (tid == 0) {
      while (__hip_atomic_load(cnt, __ATOMIC_ACQUIRE, __HIP_MEMORY_SCOPE_AGENT) < 1024) {
        __builtin_amdgcn_s_sleep(8);
      }
    }
    __syncthreads();
    __threadfence();
    __shared__ float stl[C3_ * 2];
    const int b = fb >> 3, sl = fb & 7;
    const float* sraw = wsm + OFF_SRAW;
    if (tid < 64) {
      const int c = tid;
      const float* r = sraw + ((size_t)(b * 64 + c) * 4) * 6;
      float sI = 0.f, qI = 0.f, sX = 0.f, qX = 0.f, sY = 0.f, qY = 0.f;
      #pragma unroll
      for (int q = 0; q < 4; ++q) {
        sI += r[q * 6 + 0]; qI += r[q * 6 + 1];
        sX += r[q * 6 + 2]; qX += r[q * 6 + 3];
        sY += r[q * 6 + 4]; qY += r[q * 6 + 5];
      }
      const float n = 1.f / 16384.f;
      float m;
      m = sI * n; stl[c * 2] = m;           stl[c * 2 + 1] = rsqrtf(qI * n - m * m + EPS_);
      const int cx = 64 + 2 * c, cy = cx + 1;
      m = sX * n; stl[cx * 2] = m;          stl[cx * 2 + 1] = rsqrtf(qX * n - m * m + EPS_);
      m = sY * n; stl[cy * 2] = m;          stl[cy * 2 + 1] = rsqrtf(qY * n - m * m + EPS_);
    }
    __syncthreads();

    const float* hyp = wsm + OFF_HYP + (size_t)b * HYP_;
    unsigned short* wfin = (unsigned short*)(wsm + OFF_WFIN) + (size_t)b * 24576;
    unsigned short* wfsh = (unsigned short*)(wsm + OFF_WFSH) + (size_t)b * 24576;
    unsigned short* wfmid = (unsigned short*)(wsm + OFF_WFMID) + (size_t)b * 8192;
    unsigned short* wfout = (unsigned short*)(wsm + OFF_WFOUT) + (size_t)b * 8192;
    float* abIn = wsm + OFF_ABIN + b * 64;
    float* abSh = wsm + OFF_ABSH + b * 64;

    if (sl < 6) {
      const int base = sl * 2048;
      for (int i = tid; i < 2048; i += 256) {
        int idx = base + i;
        int j = idx & 7, ch = (idx >> 3) & 63, g2 = (idx >> 9) & 3, ks = idx >> 11;
        int k = ks * 32 + g2 * 8 + j;
        int fbx = ((ks * 4 + g2) * 64 + ch) * 16;
        float inv = stl[k * 2 + 1];
        unsigned short h, l;
        split2(hyp[OFFI_WIN + ch * C3_ + k] * inv, h, l);
        wfin[fbx + j] = h; wfin[fbx + 8 + j] = l;
        split2(hyp[OFFI_WSH + ch * C3_ + k] * inv, h, l);
        wfsh[fbx + j] = h; wfsh[fbx + 8 + j] = l;
      }
    } else if (sl == 6) {
      for (int idx = tid; idx < 4096; idx += 256) {
        int j = idx & 7, ch = (idx >> 3) & 63, g2 = (idx >> 9) & 3, ks = idx >> 11;
        int k = ks * 32 + g2 * 8 + j;
        int fbx = ((ks * 4 + g2) * 64 + ch) * 16;
        unsigned short h, l;
        split2(hyp[OFFI_WMID + ch * 64 + k], h, l);
        wfmid[fbx + j] = h; wfmid[fbx + 8 + j] = l;
        split2(hyp[OFFI_WOUT + ch * 64 + k], h, l);
        wfout[fbx + j] = h; wfout[fbx + 8 + j] = l;
      }
    } else {
      if (tid < 64) {
        int o = tid;
        float s1 = 0.f, s2 = 0.f;
        for (int cc = 0; cc < C3_; ++cc) {
          float m = stl[cc * 2] * stl[cc * 2 + 1];
          s1 = __builtin_fmaf(hyp[OFFI_WIN + o * C3_ + cc], m, s1);
          s2 = __builtin_fmaf(hyp[OFFI_WSH + o * C3_ + cc], m, s2);
        }
        abIn[o] = hyp[OFFI_BIN + o] - s1;
        abSh[o] = hyp[OFFI_BSH + o] - s2;
      }
    }
    return;
  }

  // ---------- worker: SinSobel -> packed split-bf16 gx/gy + raw partials ----------
  const float* outb = wsm + OFF_OUT;
  unsigned int* sob = (unsigned int*)(wsm + OFF_SOB);
  float* sraw = wsm + OFF_SRAW;
  const int q = bi & 3, c = (bi >> 2) & 63, b = bi >> 8;
  const int col = tid & 127;
  const int r0 = q * 32 + (tid >> 7) * 16;
  const float* P = outb + ((size_t)(b * F_ + c)) * NPIX_;
  unsigned int* ygx = sob + ((size_t)(b * 128 + 2 * c)) * NPIX_;
  unsigned int* ygy = ygx + NPIX_;

  float sI = 0.f, qI = 0.f, sX = 0.f, qX = 0.f, sY = 0.f, qY = 0.f;
  float hd_m1, hd_0, hd_p1, hs_m2, hs_m1, hs_0, hs_p1;
  float td, tc;
  hline_z(P, r0 - 2, col, td, hs_m2, tc);
  hline_z(P, r0 - 1, col, hd_m1, hs_m1, tc);
  hline_z(P, r0, col, hd_0, hs_0, tc);
  sI += tc; qI += tc * tc;
  hline_z(P, r0 + 1, col, hd_p1, hs_p1, tc);
  sI += tc; qI += tc * tc;

  for (int i = 0; i < 16; ++i) {
    const int r = r0 + i;
    const int nr = r + 2;
    float hd_new, hs_new, cnew;
    hline_z(P, nr, col, hd_new, hs_new, cnew);
    if (nr <= r0 + 15) { sI += cnew; qI += cnew * cnew; }
    float gxv = R_ * (hd_m1 + hd_p1) + hd_0;
    float gyv = -hs_m2 - R_ * hs_m1 + R_ * hs_p1 + hs_new;
    const int o = r * HH_ + col;
    unsigned short h, l;
    split2(gxv, h, l);
    ygx[o] = ((unsigned)h << 16) | l;
    split2(gyv, h, l);
    ygy[o] = ((unsigned)h << 16) | l;
    sX += gxv; qX += gxv * gxv;
    sY += gyv; qY += gyv * gyv;
    hd_m1 = hd_0; hd_0 = hd_p1; hd_p1 = hd_new;
    hs_m2 = hs_m1; hs_m1 = hs_0; hs_0 = hs_p1; hs_p1 = hs_new;
  }
  __syncthreads();
  float tI = blockReduceSum(sI, scr);
  float tQI = blockReduceSum(qI, scr);
  float tX = blockReduceSum(sX, scr);
  float tQX = blockReduceSum(qX, scr);
  float tY = blockReduceSum(sY, scr);
  float tQY = blockReduceSum(qY, scr);
  if (tid == 0) {
    float* r = sraw + (size_t)bi * 6;
    r[0] = tI; r[1] = tQI; r[2] = tX; r[3] = tQX; r[4] = tY; r[5] = tQY;
    __threadfence();
    atomicAdd(cnt, 1);
  }
}

// ---------------- MFMA dynamic MLP, split-bf16 (unchanged from R4) ----------------
__global__ __launch_bounds__(256, 2) void mlp_mfma_kernel(
    float* __restrict__ outb, const unsigned int* __restrict__ sobu,
    const float* __restrict__ wsf, const float* __restrict__ leak) {
  __shared__ unsigned short yhi[64 * 200];
  __shared__ unsigned short ylo[64 * 200];
  __shared__ unsigned short hhi[64 * 72];
  __shared__ unsigned short hlo[64 * 72];
  const int bi = blockIdx.x;
  const int b = bi >> 8, t = bi & 255;
  const int px0 = t * 64;
  const int tid = threadIdx.x;

  const float* ob = outb + (size_t)b * F_ * NPIX_;
  const unsigned int* sbp = sobu + (size_t)b * 128 * NPIX_;
  #pragma unroll
  for (int it = 0; it < 12; ++it) {
    int ci = it * 256 + tid;
    int k = ci >> 4, pq = ci & 15;
    int kk = k ^ ((pq >> 1) << 3);
    unsigned short* ph = &yhi[(pq * 4) * 200 + kk];
    unsigned short* pl = &ylo[(pq * 4) * 200 + kk];
    if (k < 64) {
      float4 f = *(const float4*)(ob + (size_t)k * NPIX_ + px0 + pq * 4);
      unsigned short h, l;
      split2(f.x, h, l); ph[0 * 200] = h; pl[0 * 200] = l;
      split2(f.y, h, l); ph[1 * 200] = h; pl[1 * 200] = l;
      split2(f.z, h, l); ph[2 * 200] = h; pl[2 * 200] = l;
      split2(f.w, h, l); ph[3 * 200] = h; pl[3 * 200] = l;
    } else {
      uint4 v = *(const uint4*)(sbp + (size_t)(k - 64) * NPIX_ + px0 + pq * 4);
      ph[0 * 200] = (unsigned short)(v.x >> 16); pl[0 * 200] = (unsigned short)(v.x & 0xffff);
      ph[1 * 200] = (unsigned short)(v.y >> 16); pl[1 * 200] = (unsigned short)(v.y & 0xffff);
      ph[2 * 200] = (unsigned short)(v.z >> 16); pl[2 * 200] = (unsigned short)(v.z & 0xffff);
      ph[3 * 200] = (unsigned short)(v.w >> 16); pl[3 * 200] = (unsigned short)(v.w & 0xffff);
    }
  }
  __syncthreads();

  const int wave = tid >> 6, lane = tid & 63;
  const int lrow = lane & 15, g = lane >> 4;
  const int pxl = wave * 16 + lrow;
  const int sw = (pxl >> 3) << 3;
  const float lf = fminf(fmaxf(leak[0], 0.001f), 1000.f);
  const float* abIn = wsf + OFF_ABIN + b * 64;
  const float* abSh = wsf + OFF_ABSH + b * 64;
  const float* hyp = wsf + OFF_HYP + (size_t)b * HYP_;
  const unsigned short* wfin = (const unsigned short*)(wsf + OFF_WFIN) + (size_t)b * 24576;
  const unsigned short* wfsh = (const unsigned short*)(wsf + OFF_WFSH) + (size_t)b * 24576;
  const unsigned short* wfmid = (const unsigned short*)(wsf + OFF_WFMID) + (size_t)b * 8192;
  const unsigned short* wfout = (const unsigned short*)(wsf + OFF_WFOUT) + (size_t)b * 8192;

  f32x4 aH[4], aS[4];
  #pragma unroll
  for (int cg = 0; cg < 4; ++cg) {
    float b1 = abIn[cg * 16 + lrow], b2 = abSh[cg * 16 + lrow];
    aH[cg] = (f32x4){b1, b1, b1, b1};
    aS[cg] = (f32x4){b2, b2, b2, b2};
  }
  #pragma unroll
  for (int ks = 0; ks < 6; ++ks) {
    const int kb = pxl * 200 + ((ks * 32 + g * 8) ^ sw);
    bf16x8 ahi = *(const bf16x8*)&yhi[kb];
    bf16x8 alo = *(const bf16x8*)&ylo[kb];
    #pragma unroll
    for (int cg = 0; cg < 4; ++cg) {
      const unsigned short* p1 = wfin + (size_t)((ks * 4 + g) * 64 + cg * 16 + lrow) * 16;
      bf16x8 whi = *(const bf16x8*)p1;
      bf16x8 wlo = *(const bf16x8*)(p1 + 8);
      MM3(aH[cg], ahi, alo, whi, wlo);
      const unsigned short* p2 = wfsh + (size_t)((ks * 4 + g) * 64 + cg * 16 + lrow) * 16;
      whi = *(const bf16x8*)p2;
      wlo = *(const bf16x8*)(p2 + 8);
      MM3(aS[cg], ahi, alo, whi, wlo);
    }
  }
  #pragma unroll
  for (int cg = 0; cg < 4; ++cg) {
    #pragma unroll
    for (int j = 0; j < 4; ++j) {
      float v = aH[cg][j];
      v = (v >= 0.f) ? v : NEG_ * v;
      unsigned short h, l;
      split2(v, h, l);
      const int o = (wave * 16 + g * 4 + j) * 72 + cg * 16 + lrow;
      hhi[o] = h; hlo[o] = l;
    }
  }
  __syncthreads();
  f32x4 aM[4];
  #pragma unroll
  for (int cg = 0; cg < 4; ++cg) {
    float bm = hyp[OFFI_BMID + cg * 16 + lrow];
    aM[cg] = (f32x4){bm, bm, bm, bm};
  }
  #pragma unroll
  for (int ks = 0; ks < 2; ++ks) {
    const int kb = pxl * 72 + ks * 32 + g * 8;
    bf16x8 ahi = *(const bf16x8*)&hhi[kb];
    bf16x8 alo = *(const bf16x8*)&hlo[kb];
    #pragma unroll
    for (int cg = 0; cg < 4; ++cg) {
      const unsigned short* p1 = wfmid + (size_t)((ks * 4 + g) * 64 + cg * 16 + lrow) * 16;
      bf16x8 whi = *(const bf16x8*)p1;
      bf16x8 wlo = *(const bf16x8*)(p1 + 8);
      MM3(aM[cg], ahi, alo, whi, wlo);
    }
  }
  __syncthreads();
  #pragma unroll
  for (int cg = 0; cg < 4; ++cg) {
    #pragma unroll
    for (int j = 0; j < 4; ++j) {
      float v = aM[cg][j];
      v = (v >= 0.f) ? v : NEG_ * v;
      unsigned short h, l;
      split2(v, h, l);
      const int o = (wave * 16 + g * 4 + j) * 72 + cg * 16 + lrow;
      hhi[o] = h; hlo[o] = l;
    }
  }
  __syncthreads();
  f32x4 aO[4];
  #pragma unroll
  for (int cg = 0; cg < 4; ++cg) {
    float bo = hyp[OFFI_BOUT + cg * 16 + lrow];
    aO[cg] = (f32x4){bo, bo, bo, bo};
  }
  #pragma unroll
  for (int ks = 0; ks < 2; ++ks) {
    const int kb = pxl * 72 + ks * 32 + g * 8;
    bf16x8 ahi = *(const bf16x8*)&hhi[kb];
    bf16x8 alo = *(const bf16x8*)&hlo[kb];
    #pragma unroll
    for (int cg = 0; cg < 4; ++cg) {
      const unsigned short* p1 = wfout + (size_t)((ks * 4 + g) * 64 + cg * 16 + lrow) * 16;
      bf16x8 whi = *(const bf16x8*)p1;
      bf16x8 wlo = *(const bf16x8*)(p1 + 8);
      MM3(aO[cg], ahi, alo, whi, wlo);
    }
  }
  #pragma unroll
  for (int cg = 0; cg < 4; ++cg) {
    float* op = outb + ((size_t)(b * F_ + cg * 16 + lrow)) * NPIX_ + px0 + wave * 16 + g * 4;
    f32x4 cur = *(f32x4*)op;
    #pragma unroll
    for (int j = 0; j < 4; ++j) cur[j] += lf * (aO[cg][j] + aS[cg][j]);
    *(f32x4*)op = cur;
  }
}

// ---------------- MFMA 3x3 conv (implicit GEMM, split-bf16) -----------------------
// block = (b, tile of 64 px = half row). K = 576, tap-major k = t*64 + c_in.
// LDS: 3 halo rows x 72 cols x 64 ch, XOR-swizzled channel index.
// mode 1: dst = lrelu(conv+bias); mode 2: dst += conv+bias.
__global__ __launch_bounds__(256, 2) void conv_mfma_kernel(
    const float* __restrict__ in, const unsigned short* __restrict__ wf,
    const float* __restrict__ bias, float* __restrict__ dst, int mode) {
  __shared__ unsigned short ahi[3 * 72 * 64];
  __shared__ unsigned short alo[3 * 72 * 64];
  const int bi = blockIdx.x;
  const int b = bi >> 8, tile = bi & 255;
  const int row = tile >> 1, colbase = (tile & 1) << 6;
  const int tid = threadIdx.x;
  const float* ip = in + (size_t)b * F_ * NPIX_;

  for (int idx = tid; idx < 3456; idx += 256) {
    const int chunk = idx % 18;
    const int rowp = (idx / 18) % 3;
    const int ch = idx / 54;
    const int r2 = row - 1 + rowp;
    const int gcol0 = colbase - 4 + chunk * 4;
    float4 v;
    if (r2 < 0 || r2 > 127) {
      v = make_float4(0.f, 0.f, 0.f, 0.f);
    } else if (gcol0 >= 0 && gcol0 <= 124) {
      v = *(const float4*)(ip + (size_t)ch * NPIX_ + r2 * HH_ + gcol0);
    } else {
      const float* rp = ip + (size_t)ch * NPIX_ + r2 * HH_;
      v.x = (gcol0 >= 0 && gcol0 < 128) ? rp[gcol0] : 0.f;
      v.y = (gcol0 + 1 >= 0 && gcol0 + 1 < 128) ? rp[gcol0 + 1] : 0.f;
      v.z = (gcol0 + 2 >= 0 && gcol0 + 2 < 128) ? rp[gcol0 + 2] : 0.f;
      v.w = (gcol0 + 3 >= 0 && gcol0 + 3 < 128) ? rp[gcol0 + 3] : 0.f;
    }
    const float vv[4] = {v.x, v.y, v.z, v.w};
    #pragma unroll
    for (int e = 0; e < 4; ++e) {
      const int i = chunk * 4 + e;
      const int a = (rowp * 72 + i) * 64 + (ch ^ ((i & 7) << 3));
      unsigned short h, l;
      split2(vv[e], h, l);
      ahi[a] = h; alo[a] = l;
    }
  }
  __syncthreads();

  const int wave = tid >> 6, lane = tid & 63;
  const int lrow = lane & 15, g = lane >> 4;
  const int pxl = wave * 16 + lrow;
  f32x4 acc[4];
  #pragma unroll
  for (int cg = 0; cg < 4; ++cg) {
    float bz = bias[cg * 16 + lrow];
    acc[cg] = (f32x4){bz, bz, bz, bz};
  }
  for (int ks = 0; ks < 18; ++ks) {
    const int kbase = ks * 32 + g * 8;
    const int t = kbase >> 6, c0 = kbase & 63;
    const int dy = t / 3 - 1, dx = t % 3 - 1;
    const int i = pxl + 4 + dx;
    const int a = ((1 + dy) * 72 + i) * 64 + (c0 ^ ((i & 7) << 3));
    bf16x8 a_hi = *(const bf16x8*)&ahi[a];
    bf16x8 a_lo = *(const bf16x8*)&alo[a];
    #pragma unroll
    for (int cg = 0; cg < 4; ++cg) {
      const unsigned short* wp = wf + (size_t)((ks * 4 + g) * 64 + cg * 16 + lrow) * 16;
      bf16x8 whi = *(const bf16x8*)wp;
      bf16x8 wlo = *(const bf16x8*)(wp + 8);
      MM3(acc[cg], a_hi, a_lo, whi, wlo);
    }
  }
  #pragma unroll
  for (int cg = 0; cg < 4; ++cg) {
    float* op = dst + ((size_t)(b * F_ + cg * 16 + lrow)) * NPIX_ + row * HH_ + colbase +
                wave * 16 + g * 4;
    if (mode == 1) {
      f32x4 r;
      #pragma unroll
      for (int j = 0; j < 4; ++j) {
        float v = acc[cg][j];
        r[j] = (v >= 0.f) ? v : NEG_ * v;
      }
      *(f32x4*)op = r;
    } else {
      f32x4 cur = *(f32x4*)op;
      #pragma unroll
      for (int j = 0; j < 4; ++j) cur[j] += acc[cg][j];
      *(f32x4*)op = cur;
    }
  }
}

// ---------------- final image conv (3 outputs, VALU) ------------------------------
__global__ __launch_bounds__(256, 4) void convimg_kernel(
    const float* __restrict__ outb, const float* __restrict__ wT,
    const float* __restrict__ bias, float* __restrict__ img) {
  __shared__ float part[2 * 128 * 3];
  const int bi = blockIdx.x;
  const int b = bi >> 7, pxb = bi & 127;
  const int tid = threadIdx.x;
  const int px = tid & 127;
  const int hf = __builtin_amdgcn_readfirstlane(tid >> 7);
  const int p = pxb * 128 + px;
  const int row = p >> 7, col = p & 127;
  float a0 = 0.f, a1 = 0.f, a2 = 0.f;
  const float* ip = outb + (size_t)b * F_ * NPIX_;
  for (int cc = 0; cc < 32; ++cc) {
    const int c = hf * 32 + cc;
    const float* pl = ip + (size_t)c * NPIX_;
    #pragma unroll
    for (int t = 0; t < 9; ++t) {
      const int dy = t / 3 - 1, dx = t % 3 - 1;
      const int r2 = row + dy, c2 = col + dx;
      float v = (r2 >= 0 && r2 < 128 && c2 >= 0 && c2 < 128) ? pl[r2 * HH_ + c2] : 0.f;
      const float* wp = wT + (c * 9 + t) * 3;
      a0 = __builtin_fmaf(v, wp[0], a0);
      a1 = __builtin_fmaf(v, wp[1], a1);
      a2 = __builtin_fmaf(v, wp[2], a2);
    }
  }
  part[(hf * 128 + px) * 3 + 0] = a0;
  part[(hf * 128 + px) * 3 + 1] = a1;
  part[(hf * 128 + px) * 3 + 2] = a2;
  __syncthreads();
  if (hf == 0) {
    float r0 = a0 + part[(128 + px) * 3 + 0] + bias[0];
    float r1 = a1 + part[(128 + px) * 3 + 1] + bias[1];
    float r2 = a2 + part[(128 + px) * 3 + 2] + bias[2];
    img[((size_t)b * 3 + 0) * NPIX_ + p] = fminf(fmaxf(r0, -1.f), 1.f);
    img[((size_t)b * 3 + 1) * NPIX_ + p] = fminf(fmaxf(r1, -1.f), 1.f);
    img[((size_t)b * 3 + 2) * NPIX_ + p] = fminf(fmaxf(r2, -1.f), 1.f);
  }
}

extern "C" void kernel_launch(void* const* d_in, const int* in_sizes, int n_in,
                              void* d_out, int out_size, void* d_ws, size_t ws_size,
                              hipStream_t stream) {
  const float* lat = (const float*)d_in[0];
  const float* ca_init = (const float*)d_in[1];
  const float* leak = (const float*)d_in[2];
  const float* hyper_w = (const float*)d_in[3];
  const float* hyper_b = (const float*)d_in[4];
  const float* res_w1 = (const float*)d_in[5];
  const float* res_b1 = (const float*)d_in[6];
  const float* res_w2 = (const float*)d_in[7];
  const float* res_b2 = (const float*)d_in[8];
  const float* img_w = (const float*)d_in[9];
  const float* img_b = (const float*)d_in[10];
  float* out = (float*)d_out;
  float* ws = (float*)d_ws;
  unsigned int* sobu = (unsigned int*)(ws + OFF_SOB);

  hipMemsetAsync(ws + OFF_CNT, 0, 16 * sizeof(int), stream);
  hyper_gemm_kernel<<<(HYP_ + 3) / 4, 256, 0, stream>>>(lat, hyper_w, hyper_b, ws + OFF_HYP);
  prep_convw_kernel<<<144, 256, 0, stream>>>(res_w1, res_w2, img_w,
                                             (unsigned short*)(ws + OFF_CW1),
                                             (unsigned short*)(ws + OFF_CW2),
                                             ws + OFF_CWIMG);
  hipMemcpyAsync(ws + OFF_OUT, ca_init, (size_t)B_ * F_ * NPIX_ * sizeof(float),
                 hipMemcpyDeviceToDevice, stream);

  for (int st = 0; st < 16; ++st) {
    sobel_wadj_kernel<<<1056, 256, 0, stream>>>(ws, st);
    mlp_mfma_kernel<<<1024, 256, 0, stream>>>(ws + OFF_OUT, sobu, ws, leak);
  }

  conv_mfma_kernel<<<1024, 256, 0, stream>>>(ws + OFF_OUT, (const unsigned short*)(ws + OFF_CW1),
                                             res_b1, (float*)(ws + OFF_TMP), 1);
  conv_mfma_kernel<<<1024, 256, 0, stream>>>((const float*)(ws + OFF_TMP),
                                             (const unsigned short*)(ws + OFF_CW2),
                                             res_b2, ws + OFF_OUT, 2);
  convimg_kernel<<<512, 256, 0, stream>>>(ws + OFF_OUT, ws + OFF_CWIMG, img_b, out);
}

// Round 6
// 1388.440 us; speedup vs baseline: 1.4421x; 1.4421x over previous
//
#include <hip/hip_runtime.h>
#include <cstddef>

#define R_ 0.70710678118654752f
#define NEG_ 0.2f
#define EPS_ 1e-5f

constexpr int F_ = 64, C3_ = 192, HH_ = 128, NPIX_ = 16384, B_ = 4, LAT_ = 512, HYP_ = 33024;
// intra-row offsets inside one sample's hypernet output
constexpr int OFFI_WIN = 0, OFFI_BIN = 12288, OFFI_WMID = 12352, OFFI_BMID = 16448,
              OFFI_WOUT = 16512, OFFI_BOUT = 20608, OFFI_WSH = 20672, OFFI_BSH = 32960;
// workspace layout (float offsets)
constexpr size_t OFF_HYP = 0;         // 132096
constexpr size_t OFF_ABIN = 132096;   // 256
constexpr size_t OFF_ABSH = 132352;   // 256
constexpr size_t OFF_SRAW = 134144;   // 6144
constexpr size_t OFF_WFIN = 140288;   // 4*24576 ushort = 49152 floats (hi/lo frag pairs)
constexpr size_t OFF_WFSH = 189440;   // 49152
constexpr size_t OFF_WFMID = 238592;  // 4*8192 ushort = 16384 floats
constexpr size_t OFF_WFOUT = 254976;  // 16384
constexpr size_t OFF_CW1 = 271360;    // 73728 ushort = 36864 floats (conv1 frag pairs)
constexpr size_t OFF_CW2 = 308224;    // 36864
constexpr size_t OFF_CWIMG = 345088;  // 1728
constexpr size_t OFF_OUT = 346816;    // 4194304
constexpr size_t OFF_SOB = 4541120;   // 4*128*16384 packed-uint = 8388608 "floats"
constexpr size_t OFF_TMP = OFF_SOB;   // epilogue h (fp32, 4194304) aliases sob
// total = 12,929,728 floats = 51.7 MB

typedef short bf16x8 __attribute__((ext_vector_type(8)));
typedef float f32x4 __attribute__((ext_vector_type(4)));

// fp32 -> bf16 (RNE)
static __device__ __forceinline__ unsigned short f2b(float v) {
  unsigned u = __builtin_bit_cast(unsigned, v);
  u += 0x7fffu + ((u >> 16) & 1u);
  return (unsigned short)(u >> 16);
}
static __device__ __forceinline__ float b2f(unsigned short h) {
  return __builtin_bit_cast(float, ((unsigned)h) << 16);
}
static __device__ __forceinline__ void split2(float v, unsigned short& hi, unsigned short& lo) {
  hi = f2b(v);
  lo = f2b(v - b2f(hi));
}

// triple-MFMA split-bf16 product: acc += Ahi*Whi + Ahi*Wlo + Alo*Whi
#define MM3(acc, ahi, alo, whi, wlo)                                        \
  acc = __builtin_amdgcn_mfma_f32_16x16x32_bf16(ahi, whi, acc, 0, 0, 0);    \
  acc = __builtin_amdgcn_mfma_f32_16x16x32_bf16(ahi, wlo, acc, 0, 0, 0);    \
  acc = __builtin_amdgcn_mfma_f32_16x16x32_bf16(alo, whi, acc, 0, 0, 0);

// ---------------- hypernetwork GEMM ----------------------------------------------
__global__ __launch_bounds__(256) void hyper_gemm_kernel(
    const float* __restrict__ lat, const float* __restrict__ hw,
    const float* __restrict__ hb, float* __restrict__ hyp) {
  __shared__ float slat[B_ * LAT_];
  const int tid = threadIdx.x;
  for (int i = tid; i < B_ * LAT_; i += 256) slat[i] = lat[i];
  __syncthreads();
  const int wave = tid >> 6, lane = tid & 63;
  const int j = blockIdx.x * 4 + wave;
  if (j >= HYP_) return;
  const float* wr = hw + (size_t)j * LAT_;
  float a0 = 0.f, a1 = 0.f, a2 = 0.f, a3 = 0.f;
  for (int i = 0; i < LAT_; i += 64) {
    float w = wr[i + lane];
    a0 = __builtin_fmaf(w, slat[0 * LAT_ + i + lane], a0);
    a1 = __builtin_fmaf(w, slat[1 * LAT_ + i + lane], a1);
    a2 = __builtin_fmaf(w, slat[2 * LAT_ + i + lane], a2);
    a3 = __builtin_fmaf(w, slat[3 * LAT_ + i + lane], a3);
  }
  #pragma unroll
  for (int off = 32; off; off >>= 1) {
    a0 += __shfl_down(a0, off, 64);
    a1 += __shfl_down(a1, off, 64);
    a2 += __shfl_down(a2, off, 64);
    a3 += __shfl_down(a3, off, 64);
  }
  if (lane == 0) {
    float b = hb[j];
    hyp[0 * HYP_ + j] = a0 + b;
    hyp[1 * HYP_ + j] = a1 + b;
    hyp[2 * HYP_ + j] = a2 + b;
    hyp[3 * HYP_ + j] = a3 + b;
  }
}

// ---------------- conv weights -> split-bf16 frag layout (+ img transpose) --------
__global__ __launch_bounds__(256) void prep_convw_kernel(
    const float* __restrict__ w1, const float* __restrict__ w2,
    const float* __restrict__ wi, unsigned short* __restrict__ wf1,
    unsigned short* __restrict__ wf2, float* __restrict__ wit) {
  const int idx = blockIdx.x * 256 + threadIdx.x;
  if (idx < 36864) {
    int j = idx & 7, ch = (idx >> 3) & 63, fg = idx >> 9;  // fg = ks*4+g
    int k = (fg >> 2) * 32 + (fg & 3) * 8 + j;
    int c = k & 63, t = k >> 6;
    int fb = (fg * 64 + ch) * 16;
    unsigned short h, l;
    split2(w1[(ch * 64 + c) * 9 + t], h, l);
    wf1[fb + j] = h; wf1[fb + 8 + j] = l;
    split2(w2[(ch * 64 + c) * 9 + t], h, l);
    wf2[fb + j] = h; wf2[fb + 8 + j] = l;
  }
  if (idx < 64 * 9 * 3) {
    int k = idx % 3, rest = idx / 3;
    int t = rest % 9, c = rest / 9;
    wit[idx] = wi[(k * 64 + c) * 9 + t];
  }
}

// ---------------- block reduction helper ------------------------------------------
__device__ __forceinline__ float blockReduceSum(float v, float* scratch) {
  const int tid = threadIdx.x;
  #pragma unroll
  for (int off = 32; off; off >>= 1) v += __shfl_down(v, off, 64);
  if ((tid & 63) == 0) scratch[tid >> 6] = v;
  __syncthreads();
  float r = scratch[0] + scratch[1] + scratch[2] + scratch[3];
  __syncthreads();
  return r;
}

__device__ __forceinline__ void hline_z(const float* __restrict__ P, int rr, int col,
                                        float& hdv, float& hsv, float& cv) {
  if (rr < 0 || rr > 127) { hdv = 0.f; hsv = 0.f; cv = 0.f; return; }
  const float* rp = P + rr * HH_;
  float vm2 = (col >= 2) ? rp[col - 2] : 0.f;
  float vm1 = (col >= 1) ? rp[col - 1] : 0.f;
  float v0 = rp[col];
  float vp1 = (col <= 126) ? rp[col + 1] : 0.f;
  float vp2 = (col <= 125) ? rp[col + 2] : 0.f;
  hdv = -vm2 - R_ * vm1 + R_ * vp1 + vp2;
  hsv = R_ * vm1 + v0 + R_ * vp1;
  cv = v0;
}

// ---------------- SinSobel -> packed split-bf16 gx/gy + raw IN partials -----------
__global__ __launch_bounds__(256) void sobel_stats_kernel(
    const float* __restrict__ outb, unsigned int* __restrict__ sob,
    float* __restrict__ sraw) {
  __shared__ float scr[4];
  const int bi = blockIdx.x;
  const int q = bi & 3, c = (bi >> 2) & 63, b = bi >> 8;
  const int tid = threadIdx.x;
  const int col = tid & 127;
  const int r0 = q * 32 + (tid >> 7) * 16;
  const float* P = outb + ((size_t)(b * F_ + c)) * NPIX_;
  unsigned int* ygx = sob + ((size_t)(b * 128 + 2 * c)) * NPIX_;
  unsigned int* ygy = ygx + NPIX_;

  float sI = 0.f, qI = 0.f, sX = 0.f, qX = 0.f, sY = 0.f, qY = 0.f;
  float hd_m1, hd_0, hd_p1, hs_m2, hs_m1, hs_0, hs_p1;
  float td, tc;
  hline_z(P, r0 - 2, col, td, hs_m2, tc);
  hline_z(P, r0 - 1, col, hd_m1, hs_m1, tc);
  hline_z(P, r0, col, hd_0, hs_0, tc);
  sI += tc; qI += tc * tc;
  hline_z(P, r0 + 1, col, hd_p1, hs_p1, tc);
  sI += tc; qI += tc * tc;

  for (int i = 0; i < 16; ++i) {
    const int r = r0 + i;
    const int nr = r + 2;
    float hd_new, hs_new, cnew;
    hline_z(P, nr, col, hd_new, hs_new, cnew);
    if (nr <= r0 + 15) { sI += cnew; qI += cnew * cnew; }
    float gxv = R_ * (hd_m1 + hd_p1) + hd_0;
    float gyv = -hs_m2 - R_ * hs_m1 + R_ * hs_p1 + hs_new;
    const int o = r * HH_ + col;
    unsigned short h, l;
    split2(gxv, h, l);
    ygx[o] = ((unsigned)h << 16) | l;
    split2(gyv, h, l);
    ygy[o] = ((unsigned)h << 16) | l;
    sX += gxv; qX += gxv * gxv;
    sY += gyv; qY += gyv * gyv;
    hd_m1 = hd_0; hd_0 = hd_p1; hd_p1 = hd_new;
    hs_m2 = hs_m1; hs_m1 = hs_0; hs_0 = hs_p1; hs_p1 = hs_new;
  }
  __syncthreads();
  float tI = blockReduceSum(sI, scr);
  float tQI = blockReduceSum(qI, scr);
  float tX = blockReduceSum(sX, scr);
  float tQX = blockReduceSum(qX, scr);
  float tY = blockReduceSum(sY, scr);
  float tQY = blockReduceSum(qY, scr);
  if (tid == 0) {
    float* r = sraw + (size_t)bi * 6;
    r[0] = tI; r[1] = tQI; r[2] = tX; r[3] = tQX; r[4] = tY; r[5] = tQY;
  }
}

// ---------------- finalize stats + emit split-bf16 frag weights -------------------
// grid = 32: (b, slice). frag pair layout: wf[fb*16 + j] = hi, wf[fb*16+8+j] = lo,
// fb = (ks*4+g)*64 + ch, k = ks*32 + g*8 + j
__global__ __launch_bounds__(256) void wadjust_kernel(float* wsm) {
  __shared__ float stl[C3_ * 2];
  const int b = blockIdx.x >> 3, sl = blockIdx.x & 7;
  const int tid = threadIdx.x;
  const float* sraw = wsm + OFF_SRAW;
  if (tid < 64) {
    const int c = tid;
    const float* r = sraw + ((size_t)(b * 64 + c) * 4) * 6;
    float sI = 0.f, qI = 0.f, sX = 0.f, qX = 0.f, sY = 0.f, qY = 0.f;
    #pragma unroll
    for (int q = 0; q < 4; ++q) {
      sI += r[q * 6 + 0]; qI += r[q * 6 + 1];
      sX += r[q * 6 + 2]; qX += r[q * 6 + 3];
      sY += r[q * 6 + 4]; qY += r[q * 6 + 5];
    }
    const float n = 1.f / 16384.f;
    float m;
    m = sI * n; stl[c * 2] = m;           stl[c * 2 + 1] = rsqrtf(qI * n - m * m + EPS_);
    const int cx = 64 + 2 * c, cy = cx + 1;
    m = sX * n; stl[cx * 2] = m;          stl[cx * 2 + 1] = rsqrtf(qX * n - m * m + EPS_);
    m = sY * n; stl[cy * 2] = m;          stl[cy * 2 + 1] = rsqrtf(qY * n - m * m + EPS_);
  }
  __syncthreads();

  const float* hyp = wsm + OFF_HYP + (size_t)b * HYP_;
  unsigned short* wfin = (unsigned short*)(wsm + OFF_WFIN) + (size_t)b * 24576;
  unsigned short* wfsh = (unsigned short*)(wsm + OFF_WFSH) + (size_t)b * 24576;
  unsigned short* wfmid = (unsigned short*)(wsm + OFF_WFMID) + (size_t)b * 8192;
  unsigned short* wfout = (unsigned short*)(wsm + OFF_WFOUT) + (size_t)b * 8192;
  float* abIn = wsm + OFF_ABIN + b * 64;
  float* abSh = wsm + OFF_ABSH + b * 64;

  if (sl < 6) {
    const int base = sl * 2048;
    for (int i = tid; i < 2048; i += 256) {
      int idx = base + i;
      int j = idx & 7, ch = (idx >> 3) & 63, g2 = (idx >> 9) & 3, ks = idx >> 11;
      int k = ks * 32 + g2 * 8 + j;
      int fbx = ((ks * 4 + g2) * 64 + ch) * 16;
      float inv = stl[k * 2 + 1];
      unsigned short h, l;
      split2(hyp[OFFI_WIN + ch * C3_ + k] * inv, h, l);
      wfin[fbx + j] = h; wfin[fbx + 8 + j] = l;
      split2(hyp[OFFI_WSH + ch * C3_ + k] * inv, h, l);
      wfsh[fbx + j] = h; wfsh[fbx + 8 + j] = l;
    }
  } else if (sl == 6) {
    for (int idx = tid; idx < 4096; idx += 256) {
      int j = idx & 7, ch = (idx >> 3) & 63, g2 = (idx >> 9) & 3, ks = idx >> 11;
      int k = ks * 32 + g2 * 8 + j;
      int fbx = ((ks * 4 + g2) * 64 + ch) * 16;
      unsigned short h, l;
      split2(hyp[OFFI_WMID + ch * 64 + k], h, l);
      wfmid[fbx + j] = h; wfmid[fbx + 8 + j] = l;
      split2(hyp[OFFI_WOUT + ch * 64 + k], h, l);
      wfout[fbx + j] = h; wfout[fbx + 8 + j] = l;
    }
  } else {
    if (tid < 64) {
      int o = tid;
      float s1 = 0.f, s2 = 0.f;
      for (int cc = 0; cc < C3_; ++cc) {
        float m = stl[cc * 2] * stl[cc * 2 + 1];
        s1 = __builtin_fmaf(hyp[OFFI_WIN + o * C3_ + cc], m, s1);
        s2 = __builtin_fmaf(hyp[OFFI_WSH + o * C3_ + cc], m, s2);
      }
      abIn[o] = hyp[OFFI_BIN + o] - s1;
      abSh[o] = hyp[OFFI_BSH + o] - s2;
    }
  }
}

// ---------------- MFMA dynamic MLP, split-bf16 ------------------------------------
__global__ __launch_bounds__(256, 2) void mlp_mfma_kernel(
    float* __restrict__ outb, const unsigned int* __restrict__ sobu,
    const float* __restrict__ wsf, const float* __restrict__ leak) {
  __shared__ unsigned short yhi[64 * 200];
  __shared__ unsigned short ylo[64 * 200];
  __shared__ unsigned short hhi[64 * 72];
  __shared__ unsigned short hlo[64 * 72];
  const int bi = blockIdx.x;
  const int b = bi >> 8, t = bi & 255;
  const int px0 = t * 64;
  const int tid = threadIdx.x;

  const float* ob = outb + (size_t)b * F_ * NPIX_;
  const unsigned int* sbp = sobu + (size_t)b * 128 * NPIX_;
  #pragma unroll
  for (int it = 0; it < 12; ++it) {
    int ci = it * 256 + tid;
    int k = ci >> 4, pq = ci & 15;
    int kk = k ^ ((pq >> 1) << 3);
    unsigned short* ph = &yhi[(pq * 4) * 200 + kk];
    unsigned short* pl = &ylo[(pq * 4) * 200 + kk];
    if (k < 64) {
      float4 f = *(const float4*)(ob + (size_t)k * NPIX_ + px0 + pq * 4);
      unsigned short h, l;
      split2(f.x, h, l); ph[0 * 200] = h; pl[0 * 200] = l;
      split2(f.y, h, l); ph[1 * 200] = h; pl[1 * 200] = l;
      split2(f.z, h, l); ph[2 * 200] = h; pl[2 * 200] = l;
      split2(f.w, h, l); ph[3 * 200] = h; pl[3 * 200] = l;
    } else {
      uint4 v = *(const uint4*)(sbp + (size_t)(k - 64) * NPIX_ + px0 + pq * 4);
      ph[0 * 200] = (unsigned short)(v.x >> 16); pl[0 * 200] = (unsigned short)(v.x & 0xffff);
      ph[1 * 200] = (unsigned short)(v.y >> 16); pl[1 * 200] = (unsigned short)(v.y & 0xffff);
      ph[2 * 200] = (unsigned short)(v.z >> 16); pl[2 * 200] = (unsigned short)(v.z & 0xffff);
      ph[3 * 200] = (unsigned short)(v.w >> 16); pl[3 * 200] = (unsigned short)(v.w & 0xffff);
    }
  }
  __syncthreads();

  const int wave = tid >> 6, lane = tid & 63;
  const int lrow = lane & 15, g = lane >> 4;
  const int pxl = wave * 16 + lrow;
  const int sw = (pxl >> 3) << 3;
  const float lf = fminf(fmaxf(leak[0], 0.001f), 1000.f);
  const float* abIn = wsf + OFF_ABIN + b * 64;
  const float* abSh = wsf + OFF_ABSH + b * 64;
  const float* hyp = wsf + OFF_HYP + (size_t)b * HYP_;
  const unsigned short* wfin = (const unsigned short*)(wsf + OFF_WFIN) + (size_t)b * 24576;
  const unsigned short* wfsh = (const unsigned short*)(wsf + OFF_WFSH) + (size_t)b * 24576;
  const unsigned short* wfmid = (const unsigned short*)(wsf + OFF_WFMID) + (size_t)b * 8192;
  const unsigned short* wfout = (const unsigned short*)(wsf + OFF_WFOUT) + (size_t)b * 8192;

  f32x4 aH[4], aS[4];
  #pragma unroll
  for (int cg = 0; cg < 4; ++cg) {
    float b1 = abIn[cg * 16 + lrow], b2 = abSh[cg * 16 + lrow];
    aH[cg] = (f32x4){b1, b1, b1, b1};
    aS[cg] = (f32x4){b2, b2, b2, b2};
  }
  #pragma unroll
  for (int ks = 0; ks < 6; ++ks) {
    const int kb = pxl * 200 + ((ks * 32 + g * 8) ^ sw);
    bf16x8 ahi = *(const bf16x8*)&yhi[kb];
    bf16x8 alo = *(const bf16x8*)&ylo[kb];
    #pragma unroll
    for (int cg = 0; cg < 4; ++cg) {
      const unsigned short* p1 = wfin + (size_t)((ks * 4 + g) * 64 + cg * 16 + lrow) * 16;
      bf16x8 whi = *(const bf16x8*)p1;
      bf16x8 wlo = *(const bf16x8*)(p1 + 8);
      MM3(aH[cg], ahi, alo, whi, wlo);
      const unsigned short* p2 = wfsh + (size_t)((ks * 4 + g) * 64 + cg * 16 + lrow) * 16;
      whi = *(const bf16x8*)p2;
      wlo = *(const bf16x8*)(p2 + 8);
      MM3(aS[cg], ahi, alo, whi, wlo);
    }
  }
  #pragma unroll
  for (int cg = 0; cg < 4; ++cg) {
    #pragma unroll
    for (int j = 0; j < 4; ++j) {
      float v = aH[cg][j];
      v = (v >= 0.f) ? v : NEG_ * v;
      unsigned short h, l;
      split2(v, h, l);
      const int o = (wave * 16 + g * 4 + j) * 72 + cg * 16 + lrow;
      hhi[o] = h; hlo[o] = l;
    }
  }
  __syncthreads();
  f32x4 aM[4];
  #pragma unroll
  for (int cg = 0; cg < 4; ++cg) {
    float bm = hyp[OFFI_BMID + cg * 16 + lrow];
    aM[cg] = (f32x4){bm, bm, bm, bm};
  }
  #pragma unroll
  for (int ks = 0; ks < 2; ++ks) {
    const int kb = pxl * 72 + ks * 32 + g * 8;
    bf16x8 ahi = *(const bf16x8*)&hhi[kb];
    bf16x8 alo = *(const bf16x8*)&hlo[kb];
    #pragma unroll
    for (int cg = 0; cg < 4; ++cg) {
      const unsigned short* p1 = wfmid + (size_t)((ks * 4 + g) * 64 + cg * 16 + lrow) * 16;
      bf16x8 whi = *(const bf16x8*)p1;
      bf16x8 wlo = *(const bf16x8*)(p1 + 8);
      MM3(aM[cg], ahi, alo, whi, wlo);
    }
  }
  __syncthreads();
  #pragma unroll
  for (int cg = 0; cg < 4; ++cg) {
    #pragma unroll
    for (int j = 0; j < 4; ++j) {
      float v = aM[cg][j];
      v = (v >= 0.f) ? v : NEG_ * v;
      unsigned short h, l;
      split2(v, h, l);
      const int o = (wave * 16 + g * 4 + j) * 72 + cg * 16 + lrow;
      hhi[o] = h; hlo[o] = l;
    }
  }
  __syncthreads();
  f32x4 aO[4];
  #pragma unroll
  for (int cg = 0; cg < 4; ++cg) {
    float bo = hyp[OFFI_BOUT + cg * 16 + lrow];
    aO[cg] = (f32x4){bo, bo, bo, bo};
  }
  #pragma unroll
  for (int ks = 0; ks < 2; ++ks) {
    const int kb = pxl * 72 + ks * 32 + g * 8;
    bf16x8 ahi = *(const bf16x8*)&hhi[kb];
    bf16x8 alo = *(const bf16x8*)&hlo[kb];
    #pragma unroll
    for (int cg = 0; cg < 4; ++cg) {
      const unsigned short* p1 = wfout + (size_t)((ks * 4 + g) * 64 + cg * 16 + lrow) * 16;
      bf16x8 whi = *(const bf16x8*)p1;
      bf16x8 wlo = *(const bf16x8*)(p1 + 8);
      MM3(aO[cg], ahi, alo, whi, wlo);
    }
  }
  #pragma unroll
  for (int cg = 0; cg < 4; ++cg) {
    float* op = outb + ((size_t)(b * F_ + cg * 16 + lrow)) * NPIX_ + px0 + wave * 16 + g * 4;
    f32x4 cur = *(f32x4*)op;
    #pragma unroll
    for (int j = 0; j < 4; ++j) cur[j] += lf * (aO[cg][j] + aS[cg][j]);
    *(f32x4*)op = cur;
  }
}

// ---------------- MFMA 3x3 conv (implicit GEMM, split-bf16) -----------------------
__global__ __launch_bounds__(256, 2) void conv_mfma_kernel(
    const float* __restrict__ in, const unsigned short* __restrict__ wf,
    const float* __restrict__ bias, float* __restrict__ dst, int mode) {
  __shared__ unsigned short ahi[3 * 72 * 64];
  __shared__ unsigned short alo[3 * 72 * 64];
  const int bi = blockIdx.x;
  const int b = bi >> 8, tile = bi & 255;
  const int row = tile >> 1, colbase = (tile & 1) << 6;
  const int tid = threadIdx.x;
  const float* ip = in + (size_t)b * F_ * NPIX_;

  for (int idx = tid; idx < 3456; idx += 256) {
    const int chunk = idx % 18;
    const int rowp = (idx / 18) % 3;
    const int ch = idx / 54;
    const int r2 = row - 1 + rowp;
    const int gcol0 = colbase - 4 + chunk * 4;
    float4 v;
    if (r2 < 0 || r2 > 127) {
      v = make_float4(0.f, 0.f, 0.f, 0.f);
    } else if (gcol0 >= 0 && gcol0 <= 124) {
      v = *(const float4*)(ip + (size_t)ch * NPIX_ + r2 * HH_ + gcol0);
    } else {
      const float* rp = ip + (size_t)ch * NPIX_ + r2 * HH_;
      v.x = (gcol0 >= 0 && gcol0 < 128) ? rp[gcol0] : 0.f;
      v.y = (gcol0 + 1 >= 0 && gcol0 + 1 < 128) ? rp[gcol0 + 1] : 0.f;
      v.z = (gcol0 + 2 >= 0 && gcol0 + 2 < 128) ? rp[gcol0 + 2] : 0.f;
      v.w = (gcol0 + 3 >= 0 && gcol0 + 3 < 128) ? rp[gcol0 + 3] : 0.f;
    }
    const float vv[4] = {v.x, v.y, v.z, v.w};
    #pragma unroll
    for (int e = 0; e < 4; ++e) {
      const int i = chunk * 4 + e;
      const int a = (rowp * 72 + i) * 64 + (ch ^ ((i & 7) << 3));
      unsigned short h, l;
      split2(vv[e], h, l);
      ahi[a] = h; alo[a] = l;
    }
  }
  __syncthreads();

  const int wave = tid >> 6, lane = tid & 63;
  const int lrow = lane & 15, g = lane >> 4;
  const int pxl = wave * 16 + lrow;
  f32x4 acc[4];
  #pragma unroll
  for (int cg = 0; cg < 4; ++cg) {
    float bz = bias[cg * 16 + lrow];
    acc[cg] = (f32x4){bz, bz, bz, bz};
  }
  for (int ks = 0; ks < 18; ++ks) {
    const int kbase = ks * 32 + g * 8;
    const int t = kbase >> 6, c0 = kbase & 63;
    const int dy = t / 3 - 1, dx = t % 3 - 1;
    const int i = pxl + 4 + dx;
    const int a = ((1 + dy) * 72 + i) * 64 + (c0 ^ ((i & 7) << 3));
    bf16x8 a_hi = *(const bf16x8*)&ahi[a];
    bf16x8 a_lo = *(const bf16x8*)&alo[a];
    #pragma unroll
    for (int cg = 0; cg < 4; ++cg) {
      const unsigned short* wp = wf + (size_t)((ks * 4 + g) * 64 + cg * 16 + lrow) * 16;
      bf16x8 whi = *(const bf16x8*)wp;
      bf16x8 wlo = *(const bf16x8*)(wp + 8);
      MM3(acc[cg], a_hi, a_lo, whi, wlo);
    }
  }
  #pragma unroll
  for (int cg = 0; cg < 4; ++cg) {
    float* op = dst + ((size_t)(b * F_ + cg * 16 + lrow)) * NPIX_ + row * HH_ + colbase +
                wave * 16 + g * 4;
    if (mode == 1) {
      f32x4 r;
      #pragma unroll
      for (int j = 0; j < 4; ++j) {
        float v = acc[cg][j];
        r[j] = (v >= 0.f) ? v : NEG_ * v;
      }
      *(f32x4*)op = r;
    } else {
      f32x4 cur = *(f32x4*)op;
      #pragma unroll
      for (int j = 0; j < 4; ++j) cur[j] += acc[cg][j];
      *(f32x4*)op = cur;
    }
  }
}

// ---------------- final image conv (3 outputs, VALU) ------------------------------
__global__ __launch_bounds__(256, 4) void convimg_kernel(
    const float* __restrict__ outb, const float* __restrict__ wT,
    const float* __restrict__ bias, float* __restrict__ img) {
  __shared__ float part[2 * 128 * 3];
  const int bi = blockIdx.x;
  const int b = bi >> 7, pxb = bi & 127;
  const int tid = threadIdx.x;
  const int px = tid & 127;
  const int hf = __builtin_amdgcn_readfirstlane(tid >> 7);
  const int p = pxb * 128 + px;
  const int row = p >> 7, col = p & 127;
  float a0 = 0.f, a1 = 0.f, a2 = 0.f;
  const float* ip = outb + (size_t)b * F_ * NPIX_;
  for (int cc = 0; cc < 32; ++cc) {
    const int c = hf * 32 + cc;
    const float* pl = ip + (size_t)c * NPIX_;
    #pragma unroll
    for (int t = 0; t < 9; ++t) {
      const int dy = t / 3 - 1, dx = t % 3 - 1;
      const int r2 = row + dy, c2 = col + dx;
      float v = (r2 >= 0 && r2 < 128 && c2 >= 0 && c2 < 128) ? pl[r2 * HH_ + c2] : 0.f;
      const float* wp = wT + (c * 9 + t) * 3;
      a0 = __builtin_fmaf(v, wp[0], a0);
      a1 = __builtin_fmaf(v, wp[1], a1);
      a2 = __builtin_fmaf(v, wp[2], a2);
    }
  }
  part[(hf * 128 + px) * 3 + 0] = a0;
  part[(hf * 128 + px) * 3 + 1] = a1;
  part[(hf * 128 + px) * 3 + 2] = a2;
  __syncthreads();
  if (hf == 0) {
    float r0 = a0 + part[(128 + px) * 3 + 0] + bias[0];
    float r1 = a1 + part[(128 + px) * 3 + 1] + bias[1];
    float r2 = a2 + part[(128 + px) * 3 + 2] + bias[2];
    img[((size_t)b * 3 + 0) * NPIX_ + p] = fminf(fmaxf(r0, -1.f), 1.f);
    img[((size_t)b * 3 + 1) * NPIX_ + p] = fminf(fmaxf(r1, -1.f), 1.f);
    img[((size_t)b * 3 + 2) * NPIX_ + p] = fminf(fmaxf(r2, -1.f), 1.f);
  }
}

extern "C" void kernel_launch(void* const* d_in, const int* in_sizes, int n_in,
                              void* d_out, int out_size, void* d_ws, size_t ws_size,
                              hipStream_t stream) {
  const float* lat = (const float*)d_in[0];
  const float* ca_init = (const float*)d_in[1];
  const float* leak = (const float*)d_in[2];
  const float* hyper_w = (const float*)d_in[3];
  const float* hyper_b = (const float*)d_in[4];
  const float* res_w1 = (const float*)d_in[5];
  const float* res_b1 = (const float*)d_in[6];
  const float* res_w2 = (const float*)d_in[7];
  const float* res_b2 = (const float*)d_in[8];
  const float* img_w = (const float*)d_in[9];
  const float* img_b = (const float*)d_in[10];
  float* out = (float*)d_out;
  float* ws = (float*)d_ws;
  unsigned int* sobu = (unsigned int*)(ws + OFF_SOB);

  hyper_gemm_kernel<<<(HYP_ + 3) / 4, 256, 0, stream>>>(lat, hyper_w, hyper_b, ws + OFF_HYP);
  prep_convw_kernel<<<144, 256, 0, stream>>>(res_w1, res_w2, img_w,
                                             (unsigned short*)(ws + OFF_CW1),
                                             (unsigned short*)(ws + OFF_CW2),
                                             ws + OFF_CWIMG);
  hipMemcpyAsync(ws + OFF_OUT, ca_init, (size_t)B_ * F_ * NPIX_ * sizeof(float),
                 hipMemcpyDeviceToDevice, stream);

  for (int st = 0; st < 16; ++st) {
    sobel_stats_kernel<<<1024, 256, 0, stream>>>(ws + OFF_OUT, sobu, ws + OFF_SRAW);
    wadjust_kernel<<<32, 256, 0, stream>>>(ws);
    mlp_mfma_kernel<<<1024, 256, 0, stream>>>(ws + OFF_OUT, sobu, ws, leak);
  }

  conv_mfma_kernel<<<1024, 256, 0, stream>>>(ws + OFF_OUT, (const unsigned short*)(ws + OFF_CW1),
                                             res_b1, (float*)(ws + OFF_TMP), 1);
  conv_mfma_kernel<<<1024, 256, 0, stream>>>((const float*)(ws + OFF_TMP),
                                             (const unsigned short*)(ws + OFF_CW2),
                                             res_b2, ws + OFF_OUT, 2);
  convimg_kernel<<<512, 256, 0, stream>>>(ws + OFF_OUT, ws + OFF_CWIMG, img_b, out);
}

// Round 7
// 1328.862 us; speedup vs baseline: 1.5068x; 1.0448x over previous
//
#include <hip/hip_runtime.h>
#include <cstddef>

#define R_ 0.70710678118654752f
#define NEG_ 0.2f
#define EPS_ 1e-5f

constexpr int F_ = 64, C3_ = 192, HH_ = 128, NPIX_ = 16384, B_ = 4, LAT_ = 512, HYP_ = 33024;
// intra-row offsets inside one sample's hypernet output
constexpr int OFFI_WIN = 0, OFFI_BIN = 12288, OFFI_WMID = 12352, OFFI_BMID = 16448,
              OFFI_WOUT = 16512, OFFI_BOUT = 20608, OFFI_WSH = 20672, OFFI_BSH = 32960;
// workspace layout (float offsets)
constexpr size_t OFF_HYP = 0;         // 132096
constexpr size_t OFF_SRAW = 134144;   // 6144
constexpr size_t OFF_WFIN = 140288;   // 4*24576 ushort = 49152 floats (hi/lo frag pairs)
constexpr size_t OFF_WFSH = 189440;   // 49152
constexpr size_t OFF_WFMID = 238592;  // 4*8192 ushort = 16384 floats
constexpr size_t OFF_WFOUT = 254976;  // 16384
constexpr size_t OFF_CW1 = 271360;    // 73728 ushort = 36864 floats (conv1 frag pairs)
constexpr size_t OFF_CW2 = 308224;    // 36864
constexpr size_t OFF_CWIMG = 345088;  // 1728
constexpr size_t OFF_OUT = 346816;    // 4194304
constexpr size_t OFF_SOB = 4541120;   // 4*128*16384 packed-uint = 8388608 "floats"
constexpr size_t OFF_TMP = OFF_SOB;   // epilogue h (fp32, 4194304) aliases sob
// total = 12,929,728 floats = 51.7 MB

typedef short bf16x8 __attribute__((ext_vector_type(8)));
typedef float f32x4 __attribute__((ext_vector_type(4)));

// fp32 -> bf16 (RNE)
static __device__ __forceinline__ unsigned short f2b(float v) {
  unsigned u = __builtin_bit_cast(unsigned, v);
  u += 0x7fffu + ((u >> 16) & 1u);
  return (unsigned short)(u >> 16);
}
static __device__ __forceinline__ float b2f(unsigned short h) {
  return __builtin_bit_cast(float, ((unsigned)h) << 16);
}
static __device__ __forceinline__ void split2(float v, unsigned short& hi, unsigned short& lo) {
  hi = f2b(v);
  lo = f2b(v - b2f(hi));
}

// triple-MFMA split-bf16 product: acc += Ahi*Whi + Ahi*Wlo + Alo*Whi
#define MM3(acc, ahi, alo, whi, wlo)                                        \
  acc = __builtin_amdgcn_mfma_f32_16x16x32_bf16(ahi, whi, acc, 0, 0, 0);    \
  acc = __builtin_amdgcn_mfma_f32_16x16x32_bf16(ahi, wlo, acc, 0, 0, 0);    \
  acc = __builtin_amdgcn_mfma_f32_16x16x32_bf16(alo, whi, acc, 0, 0, 0);

// ---------------- hypernetwork GEMM ----------------------------------------------
__global__ __launch_bounds__(256) void hyper_gemm_kernel(
    const float* __restrict__ lat, const float* __restrict__ hw,
    const float* __restrict__ hb, float* __restrict__ hyp) {
  __shared__ float slat[B_ * LAT_];
  const int tid = threadIdx.x;
  for (int i = tid; i < B_ * LAT_; i += 256) slat[i] = lat[i];
  __syncthreads();
  const int wave = tid >> 6, lane = tid & 63;
  const int j = blockIdx.x * 4 + wave;
  if (j >= HYP_) return;
  const float* wr = hw + (size_t)j * LAT_;
  float a0 = 0.f, a1 = 0.f, a2 = 0.f, a3 = 0.f;
  for (int i = 0; i < LAT_; i += 64) {
    float w = wr[i + lane];
    a0 = __builtin_fmaf(w, slat[0 * LAT_ + i + lane], a0);
    a1 = __builtin_fmaf(w, slat[1 * LAT_ + i + lane], a1);
    a2 = __builtin_fmaf(w, slat[2 * LAT_ + i + lane], a2);
    a3 = __builtin_fmaf(w, slat[3 * LAT_ + i + lane], a3);
  }
  #pragma unroll
  for (int off = 32; off; off >>= 1) {
    a0 += __shfl_down(a0, off, 64);
    a1 += __shfl_down(a1, off, 64);
    a2 += __shfl_down(a2, off, 64);
    a3 += __shfl_down(a3, off, 64);
  }
  if (lane == 0) {
    float b = hb[j];
    hyp[0 * HYP_ + j] = a0 + b;
    hyp[1 * HYP_ + j] = a1 + b;
    hyp[2 * HYP_ + j] = a2 + b;
    hyp[3 * HYP_ + j] = a3 + b;
  }
}

// ---------------- dynamic weights -> STATIC split-bf16 frag layout (once) ---------
// No stats fold: A-side normalization. grid = 4b x 7 slices.
__global__ __launch_bounds__(256) void prep_dynw_kernel(float* wsm) {
  const int b = blockIdx.x >> 3, sl = blockIdx.x & 7;
  const int tid = threadIdx.x;
  const float* hyp = wsm + OFF_HYP + (size_t)b * HYP_;
  unsigned short* wfin = (unsigned short*)(wsm + OFF_WFIN) + (size_t)b * 24576;
  unsigned short* wfsh = (unsigned short*)(wsm + OFF_WFSH) + (size_t)b * 24576;
  unsigned short* wfmid = (unsigned short*)(wsm + OFF_WFMID) + (size_t)b * 8192;
  unsigned short* wfout = (unsigned short*)(wsm + OFF_WFOUT) + (size_t)b * 8192;

  if (sl < 6) {
    const int base = sl * 2048;
    for (int i = tid; i < 2048; i += 256) {
      int idx = base + i;
      int j = idx & 7, ch = (idx >> 3) & 63, g2 = (idx >> 9) & 3, ks = idx >> 11;
      int k = ks * 32 + g2 * 8 + j;
      int fbx = ((ks * 4 + g2) * 64 + ch) * 16;
      unsigned short h, l;
      split2(hyp[OFFI_WIN + ch * C3_ + k], h, l);
      wfin[fbx + j] = h; wfin[fbx + 8 + j] = l;
      split2(hyp[OFFI_WSH + ch * C3_ + k], h, l);
      wfsh[fbx + j] = h; wfsh[fbx + 8 + j] = l;
    }
  } else if (sl == 6) {
    for (int idx = tid; idx < 4096; idx += 256) {
      int j = idx & 7, ch = (idx >> 3) & 63, g2 = (idx >> 9) & 3, ks = idx >> 11;
      int k = ks * 32 + g2 * 8 + j;
      int fbx = ((ks * 4 + g2) * 64 + ch) * 16;
      unsigned short h, l;
      split2(hyp[OFFI_WMID + ch * 64 + k], h, l);
      wfmid[fbx + j] = h; wfmid[fbx + 8 + j] = l;
      split2(hyp[OFFI_WOUT + ch * 64 + k], h, l);
      wfout[fbx + j] = h; wfout[fbx + 8 + j] = l;
    }
  }
}

// ---------------- conv weights -> split-bf16 frag layout (+ img transpose) --------
__global__ __launch_bounds__(256) void prep_convw_kernel(
    const float* __restrict__ w1, const float* __restrict__ w2,
    const float* __restrict__ wi, unsigned short* __restrict__ wf1,
    unsigned short* __restrict__ wf2, float* __restrict__ wit) {
  const int idx = blockIdx.x * 256 + threadIdx.x;
  if (idx < 36864) {
    int j = idx & 7, ch = (idx >> 3) & 63, fg = idx >> 9;  // fg = ks*4+g
    int k = (fg >> 2) * 32 + (fg & 3) * 8 + j;
    int c = k & 63, t = k >> 6;
    int fb = (fg * 64 + ch) * 16;
    unsigned short h, l;
    split2(w1[(ch * 64 + c) * 9 + t], h, l);
    wf1[fb + j] = h; wf1[fb + 8 + j] = l;
    split2(w2[(ch * 64 + c) * 9 + t], h, l);
    wf2[fb + j] = h; wf2[fb + 8 + j] = l;
  }
  if (idx < 64 * 9 * 3) {
    int k = idx % 3, rest = idx / 3;
    int t = rest % 9, c = rest / 9;
    wit[idx] = wi[(k * 64 + c) * 9 + t];
  }
}

// ---------------- block reduction helper ------------------------------------------
__device__ __forceinline__ float blockReduceSum(float v, float* scratch) {
  const int tid = threadIdx.x;
  #pragma unroll
  for (int off = 32; off; off >>= 1) v += __shfl_down(v, off, 64);
  if ((tid & 63) == 0) scratch[tid >> 6] = v;
  __syncthreads();
  float r = scratch[0] + scratch[1] + scratch[2] + scratch[3];
  __syncthreads();
  return r;
}

__device__ __forceinline__ void hline_z(const float* __restrict__ P, int rr, int col,
                                        float& hdv, float& hsv, float& cv) {
  if (rr < 0 || rr > 127) { hdv = 0.f; hsv = 0.f; cv = 0.f; return; }
  const float* rp = P + rr * HH_;
  float vm2 = (col >= 2) ? rp[col - 2] : 0.f;
  float vm1 = (col >= 1) ? rp[col - 1] : 0.f;
  float v0 = rp[col];
  float vp1 = (col <= 126) ? rp[col + 1] : 0.f;
  float vp2 = (col <= 125) ? rp[col + 2] : 0.f;
  hdv = -vm2 - R_ * vm1 + R_ * vp1 + vp2;
  hsv = R_ * vm1 + v0 + R_ * vp1;
  cv = v0;
}

// ---------------- SinSobel -> packed split-bf16 gx/gy + raw IN partials -----------
__global__ __launch_bounds__(256) void sobel_stats_kernel(
    const float* __restrict__ outb, unsigned int* __restrict__ sob,
    float* __restrict__ sraw) {
  __shared__ float scr[4];
  const int bi = blockIdx.x;
  const int q = bi & 3, c = (bi >> 2) & 63, b = bi >> 8;
  const int tid = threadIdx.x;
  const int col = tid & 127;
  const int r0 = q * 32 + (tid >> 7) * 16;
  const float* P = outb + ((size_t)(b * F_ + c)) * NPIX_;
  unsigned int* ygx = sob + ((size_t)(b * 128 + 2 * c)) * NPIX_;
  unsigned int* ygy = ygx + NPIX_;

  float sI = 0.f, qI = 0.f, sX = 0.f, qX = 0.f, sY = 0.f, qY = 0.f;
  float hd_m1, hd_0, hd_p1, hs_m2, hs_m1, hs_0, hs_p1;
  float td, tc;
  hline_z(P, r0 - 2, col, td, hs_m2, tc);
  hline_z(P, r0 - 1, col, hd_m1, hs_m1, tc);
  hline_z(P, r0, col, hd_0, hs_0, tc);
  sI += tc; qI += tc * tc;
  hline_z(P, r0 + 1, col, hd_p1, hs_p1, tc);
  sI += tc; qI += tc * tc;

  for (int i = 0; i < 16; ++i) {
    const int r = r0 + i;
    const int nr = r + 2;
    float hd_new, hs_new, cnew;
    hline_z(P, nr, col, hd_new, hs_new, cnew);
    if (nr <= r0 + 15) { sI += cnew; qI += cnew * cnew; }
    float gxv = R_ * (hd_m1 + hd_p1) + hd_0;
    float gyv = -hs_m2 - R_ * hs_m1 + R_ * hs_p1 + hs_new;
    const int o = r * HH_ + col;
    unsigned short h, l;
    split2(gxv, h, l);
    ygx[o] = ((unsigned)h << 16) | l;
    split2(gyv, h, l);
    ygy[o] = ((unsigned)h << 16) | l;
    sX += gxv; qX += gxv * gxv;
    sY += gyv; qY += gyv * gyv;
    hd_m1 = hd_0; hd_0 = hd_p1; hd_p1 = hd_new;
    hs_m2 = hs_m1; hs_m1 = hs_0; hs_0 = hs_p1; hs_p1 = hs_new;
  }
  __syncthreads();
  float tI = blockReduceSum(sI, scr);
  float tQI = blockReduceSum(qI, scr);
  float tX = blockReduceSum(sX, scr);
  float tQX = blockReduceSum(qX, scr);
  float tY = blockReduceSum(sY, scr);
  float tQY = blockReduceSum(qY, scr);
  if (tid == 0) {
    float* r = sraw + (size_t)bi * 6;
    r[0] = tI; r[1] = tQI; r[2] = tX; r[3] = tQX; r[4] = tY; r[5] = tQY;
  }
}

// ---------------- MFMA dynamic MLP, split-bf16, A-side normalization --------------
// Each block finalizes IN stats from sraw (redundant, cheap), then stages
// y_norm = (y - mu)*inv as split-bf16. Weights are the static frag buffers.
__global__ __launch_bounds__(256, 2) void mlp_mfma_kernel(
    float* __restrict__ outb, const unsigned int* __restrict__ sobu,
    const float* __restrict__ wsf, const float* __restrict__ leak) {
  __shared__ unsigned short yhi[64 * 200];
  __shared__ unsigned short ylo[64 * 200];
  __shared__ unsigned short hhi[64 * 72];
  __shared__ unsigned short hlo[64 * 72];
  __shared__ float stl[C3_ * 2];
  const int bi = blockIdx.x;
  const int b = bi >> 8, t = bi & 255;
  const int px0 = t * 64;
  const int tid = threadIdx.x;

  // finalize InstanceNorm stats for this sample (64 threads x 3 channels each)
  if (tid < 64) {
    const int c = tid;
    const float* r = wsf + OFF_SRAW + ((size_t)(b * 64 + c) * 4) * 6;
    float sI = 0.f, qI = 0.f, sX = 0.f, qX = 0.f, sY = 0.f, qY = 0.f;
    #pragma unroll
    for (int q = 0; q < 4; ++q) {
      sI += r[q * 6 + 0]; qI += r[q * 6 + 1];
      sX += r[q * 6 + 2]; qX += r[q * 6 + 3];
      sY += r[q * 6 + 4]; qY += r[q * 6 + 5];
    }
    const float n = 1.f / 16384.f;
    float m;
    m = sI * n; stl[c * 2] = m;           stl[c * 2 + 1] = rsqrtf(qI * n - m * m + EPS_);
    const int cx = 64 + 2 * c, cy = cx + 1;
    m = sX * n; stl[cx * 2] = m;          stl[cx * 2 + 1] = rsqrtf(qX * n - m * m + EPS_);
    m = sY * n; stl[cy * 2] = m;          stl[cy * 2 + 1] = rsqrtf(qY * n - m * m + EPS_);
  }
  __syncthreads();

  const float* ob = outb + (size_t)b * F_ * NPIX_;
  const unsigned int* sbp = sobu + (size_t)b * 128 * NPIX_;
  #pragma unroll
  for (int it = 0; it < 12; ++it) {
    int ci = it * 256 + tid;
    int k = ci >> 4, pq = ci & 15;
    int kk = k ^ ((pq >> 1) << 3);
    unsigned short* ph = &yhi[(pq * 4) * 200 + kk];
    unsigned short* pl = &ylo[(pq * 4) * 200 + kk];
    const float mu = stl[k * 2], inv = stl[k * 2 + 1];
    float vv[4];
    if (k < 64) {
      float4 f = *(const float4*)(ob + (size_t)k * NPIX_ + px0 + pq * 4);
      vv[0] = f.x; vv[1] = f.y; vv[2] = f.z; vv[3] = f.w;
    } else {
      uint4 v = *(const uint4*)(sbp + (size_t)(k - 64) * NPIX_ + px0 + pq * 4);
      vv[0] = b2f((unsigned short)(v.x >> 16)) + b2f((unsigned short)(v.x & 0xffff));
      vv[1] = b2f((unsigned short)(v.y >> 16)) + b2f((unsigned short)(v.y & 0xffff));
      vv[2] = b2f((unsigned short)(v.z >> 16)) + b2f((unsigned short)(v.z & 0xffff));
      vv[3] = b2f((unsigned short)(v.w >> 16)) + b2f((unsigned short)(v.w & 0xffff));
    }
    #pragma unroll
    for (int e = 0; e < 4; ++e) {
      unsigned short h, l;
      split2((vv[e] - mu) * inv, h, l);
      ph[e * 200] = h; pl[e * 200] = l;
    }
  }
  __syncthreads();

  const int wave = tid >> 6, lane = tid & 63;
  const int lrow = lane & 15, g = lane >> 4;
  const int pxl = wave * 16 + lrow;
  const int sw = (pxl >> 3) << 3;
  const float lf = fminf(fmaxf(leak[0], 0.001f), 1000.f);
  const float* hyp = wsf + OFF_HYP + (size_t)b * HYP_;
  const unsigned short* wfin = (const unsigned short*)(wsf + OFF_WFIN) + (size_t)b * 24576;
  const unsigned short* wfsh = (const unsigned short*)(wsf + OFF_WFSH) + (size_t)b * 24576;
  const unsigned short* wfmid = (const unsigned short*)(wsf + OFF_WFMID) + (size_t)b * 8192;
  const unsigned short* wfout = (const unsigned short*)(wsf + OFF_WFOUT) + (size_t)b * 8192;

  f32x4 aH[4], aS[4];
  #pragma unroll
  for (int cg = 0; cg < 4; ++cg) {
    float b1 = hyp[OFFI_BIN + cg * 16 + lrow], b2 = hyp[OFFI_BSH + cg * 16 + lrow];
    aH[cg] = (f32x4){b1, b1, b1, b1};
    aS[cg] = (f32x4){b2, b2, b2, b2};
  }
  #pragma unroll
  for (int ks = 0; ks < 6; ++ks) {
    const int kb = pxl * 200 + ((ks * 32 + g * 8) ^ sw);
    bf16x8 ahi = *(const bf16x8*)&yhi[kb];
    bf16x8 alo = *(const bf16x8*)&ylo[kb];
    #pragma unroll
    for (int cg = 0; cg < 4; ++cg) {
      const unsigned short* p1 = wfin + (size_t)((ks * 4 + g) * 64 + cg * 16 + lrow) * 16;
      bf16x8 whi = *(const bf16x8*)p1;
      bf16x8 wlo = *(const bf16x8*)(p1 + 8);
      MM3(aH[cg], ahi, alo, whi, wlo);
      const unsigned short* p2 = wfsh + (size_t)((ks * 4 + g) * 64 + cg * 16 + lrow) * 16;
      whi = *(const bf16x8*)p2;
      wlo = *(const bf16x8*)(p2 + 8);
      MM3(aS[cg], ahi, alo, whi, wlo);
    }
  }
  #pragma unroll
  for (int cg = 0; cg < 4; ++cg) {
    #pragma unroll
    for (int j = 0; j < 4; ++j) {
      float v = aH[cg][j];
      v = (v >= 0.f) ? v : NEG_ * v;
      unsigned short h, l;
      split2(v, h, l);
      const int o = (wave * 16 + g * 4 + j) * 72 + cg * 16 + lrow;
      hhi[o] = h; hlo[o] = l;
    }
  }
  __syncthreads();
  f32x4 aM[4];
  #pragma unroll
  for (int cg = 0; cg < 4; ++cg) {
    float bm = hyp[OFFI_BMID + cg * 16 + lrow];
    aM[cg] = (f32x4){bm, bm, bm, bm};
  }
  #pragma unroll
  for (int ks = 0; ks < 2; ++ks) {
    const int kb = pxl * 72 + ks * 32 + g * 8;
    bf16x8 ahi = *(const bf16x8*)&hhi[kb];
    bf16x8 alo = *(const bf16x8*)&hlo[kb];
    #pragma unroll
    for (int cg = 0; cg < 4; ++cg) {
      const unsigned short* p1 = wfmid + (size_t)((ks * 4 + g) * 64 + cg * 16 + lrow) * 16;
      bf16x8 whi = *(const bf16x8*)p1;
      bf16x8 wlo = *(const bf16x8*)(p1 + 8);
      MM3(aM[cg], ahi, alo, whi, wlo);
    }
  }
  __syncthreads();
  #pragma unroll
  for (int cg = 0; cg < 4; ++cg) {
    #pragma unroll
    for (int j = 0; j < 4; ++j) {
      float v = aM[cg][j];
      v = (v >= 0.f) ? v : NEG_ * v;
      unsigned short h, l;
      split2(v, h, l);
      const int o = (wave * 16 + g * 4 + j) * 72 + cg * 16 + lrow;
      hhi[o] = h; hlo[o] = l;
    }
  }
  __syncthreads();
  f32x4 aO[4];
  #pragma unroll
  for (int cg = 0; cg < 4; ++cg) {
    float bo = hyp[OFFI_BOUT + cg * 16 + lrow];
    aO[cg] = (f32x4){bo, bo, bo, bo};
  }
  #pragma unroll
  for (int ks = 0; ks < 2; ++ks) {
    const int kb = pxl * 72 + ks * 32 + g * 8;
    bf16x8 ahi = *(const bf16x8*)&hhi[kb];
    bf16x8 alo = *(const bf16x8*)&hlo[kb];
    #pragma unroll
    for (int cg = 0; cg < 4; ++cg) {
      const unsigned short* p1 = wfout + (size_t)((ks * 4 + g) * 64 + cg * 16 + lrow) * 16;
      bf16x8 whi = *(const bf16x8*)p1;
      bf16x8 wlo = *(const bf16x8*)(p1 + 8);
      MM3(aO[cg], ahi, alo, whi, wlo);
    }
  }
  #pragma unroll
  for (int cg = 0; cg < 4; ++cg) {
    float* op = outb + ((size_t)(b * F_ + cg * 16 + lrow)) * NPIX_ + px0 + wave * 16 + g * 4;
    f32x4 cur = *(f32x4*)op;
    #pragma unroll
    for (int j = 0; j < 4; ++j) cur[j] += lf * (aO[cg][j] + aS[cg][j]);
    *(f32x4*)op = cur;
  }
}

// ---------------- MFMA 3x3 conv (implicit GEMM, split-bf16) -----------------------
__global__ __launch_bounds__(256, 2) void conv_mfma_kernel(
    const float* __restrict__ in, const unsigned short* __restrict__ wf,
    const float* __restrict__ bias, float* __restrict__ dst, int mode) {
  __shared__ unsigned short ahi[3 * 72 * 64];
  __shared__ unsigned short alo[3 * 72 * 64];
  const int bi = blockIdx.x;
  const int b = bi >> 8, tile = bi & 255;
  const int row = tile >> 1, colbase = (tile & 1) << 6;
  const int tid = threadIdx.x;
  const float* ip = in + (size_t)b * F_ * NPIX_;

  for (int idx = tid; idx < 3456; idx += 256) {
    const int chunk = idx % 18;
    const int rowp = (idx / 18) % 3;
    const int ch = idx / 54;
    const int r2 = row - 1 + rowp;
    const int gcol0 = colbase - 4 + chunk * 4;
    float4 v;
    if (r2 < 0 || r2 > 127) {
      v = make_float4(0.f, 0.f, 0.f, 0.f);
    } else if (gcol0 >= 0 && gcol0 <= 124) {
      v = *(const float4*)(ip + (size_t)ch * NPIX_ + r2 * HH_ + gcol0);
    } else {
      const float* rp = ip + (size_t)ch * NPIX_ + r2 * HH_;
      v.x = (gcol0 >= 0 && gcol0 < 128) ? rp[gcol0] : 0.f;
      v.y = (gcol0 + 1 >= 0 && gcol0 + 1 < 128) ? rp[gcol0 + 1] : 0.f;
      v.z = (gcol0 + 2 >= 0 && gcol0 + 2 < 128) ? rp[gcol0 + 2] : 0.f;
      v.w = (gcol0 + 3 >= 0 && gcol0 + 3 < 128) ? rp[gcol0 + 3] : 0.f;
    }
    const float vv[4] = {v.x, v.y, v.z, v.w};
    #pragma unroll
    for (int e = 0; e < 4; ++e) {
      const int i = chunk * 4 + e;
      const int a = (rowp * 72 + i) * 64 + (ch ^ ((i & 7) << 3));
      unsigned short h, l;
      split2(vv[e], h, l);
      ahi[a] = h; alo[a] = l;
    }
  }
  __syncthreads();

  const int wave = tid >> 6, lane = tid & 63;
  const int lrow = lane & 15, g = lane >> 4;
  const int pxl = wave * 16 + lrow;
  f32x4 acc[4];
  #pragma unroll
  for (int cg = 0; cg < 4; ++cg) {
    float bz = bias[cg * 16 + lrow];
    acc[cg] = (f32x4){bz, bz, bz, bz};
  }
  for (int ks = 0; ks < 18; ++ks) {
    const int kbase = ks * 32 + g * 8;
    const int t = kbase >> 6, c0 = kbase & 63;
    const int dy = t / 3 - 1, dx = t % 3 - 1;
    const int i = pxl + 4 + dx;
    const int a = ((1 + dy) * 72 + i) * 64 + (c0 ^ ((i & 7) << 3));
    bf16x8 a_hi = *(const bf16x8*)&ahi[a];
    bf16x8 a_lo = *(const bf16x8*)&alo[a];
    #pragma unroll
    for (int cg = 0; cg < 4; ++cg) {
      const unsigned short* wp = wf + (size_t)((ks * 4 + g) * 64 + cg * 16 + lrow) * 16;
      bf16x8 whi = *(const bf16x8*)wp;
      bf16x8 wlo = *(const bf16x8*)(wp + 8);
      MM3(acc[cg], a_hi, a_lo, whi, wlo);
    }
  }
  #pragma unroll
  for (int cg = 0; cg < 4; ++cg) {
    float* op = dst + ((size_t)(b * F_ + cg * 16 + lrow)) * NPIX_ + row * HH_ + colbase +
                wave * 16 + g * 4;
    if (mode == 1) {
      f32x4 r;
      #pragma unroll
      for (int j = 0; j < 4; ++j) {
        float v = acc[cg][j];
        r[j] = (v >= 0.f) ? v : NEG_ * v;
      }
      *(f32x4*)op = r;
    } else {
      f32x4 cur = *(f32x4*)op;
      #pragma unroll
      for (int j = 0; j < 4; ++j) cur[j] += acc[cg][j];
      *(f32x4*)op = cur;
    }
  }
}

// ---------------- final image conv (3 outputs, VALU) ------------------------------
__global__ __launch_bounds__(256, 4) void convimg_kernel(
    const float* __restrict__ outb, const float* __restrict__ wT,
    const float* __restrict__ bias, float* __restrict__ img) {
  __shared__ float part[2 * 128 * 3];
  const int bi = blockIdx.x;
  const int b = bi >> 7, pxb = bi & 127;
  const int tid = threadIdx.x;
  const int px = tid & 127;
  const int hf = __builtin_amdgcn_readfirstlane(tid >> 7);
  const int p = pxb * 128 + px;
  const int row = p >> 7, col = p & 127;
  float a0 = 0.f, a1 = 0.f, a2 = 0.f;
  const float* ip = outb + (size_t)b * F_ * NPIX_;
  for (int cc = 0; cc < 32; ++cc) {
    const int c = hf * 32 + cc;
    const float* pl = ip + (size_t)c * NPIX_;
    #pragma unroll
    for (int t = 0; t < 9; ++t) {
      const int dy = t / 3 - 1, dx = t % 3 - 1;
      const int r2 = row + dy, c2 = col + dx;
      float v = (r2 >= 0 && r2 < 128 && c2 >= 0 && c2 < 128) ? pl[r2 * HH_ + c2] : 0.f;
      const float* wp = wT + (c * 9 + t) * 3;
      a0 = __builtin_fmaf(v, wp[0], a0);
      a1 = __builtin_fmaf(v, wp[1], a1);
      a2 = __builtin_fmaf(v, wp[2], a2);
    }
  }
  part[(hf * 128 + px) * 3 + 0] = a0;
  part[(hf * 128 + px) * 3 + 1] = a1;
  part[(hf * 128 + px) * 3 + 2] = a2;
  __syncthreads();
  if (hf == 0) {
    float r0 = a0 + part[(128 + px) * 3 + 0] + bias[0];
    float r1 = a1 + part[(128 + px) * 3 + 1] + bias[1];
    float r2 = a2 + part[(128 + px) * 3 + 2] + bias[2];
    img[((size_t)b * 3 + 0) * NPIX_ + p] = fminf(fmaxf(r0, -1.f), 1.f);
    img[((size_t)b * 3 + 1) * NPIX_ + p] = fminf(fmaxf(r1, -1.f), 1.f);
    img[((size_t)b * 3 + 2) * NPIX_ + p] = fminf(fmaxf(r2, -1.f), 1.f);
  }
}

extern "C" void kernel_launch(void* const* d_in, const int* in_sizes, int n_in,
                              void* d_out, int out_size, void* d_ws, size_t ws_size,
                              hipStream_t stream) {
  const float* lat = (const float*)d_in[0];
  const float* ca_init = (const float*)d_in[1];
  const float* leak = (const float*)d_in[2];
  const float* hyper_w = (const float*)d_in[3];
  const float* hyper_b = (const float*)d_in[4];
  const float* res_w1 = (const float*)d_in[5];
  const float* res_b1 = (const float*)d_in[6];
  const float* res_w2 = (const float*)d_in[7];
  const float* res_b2 = (const float*)d_in[8];
  const float* img_w = (const float*)d_in[9];
  const float* img_b = (const float*)d_in[10];
  float* out = (float*)d_out;
  float* ws = (float*)d_ws;
  unsigned int* sobu = (unsigned int*)(ws + OFF_SOB);

  hyper_gemm_kernel<<<(HYP_ + 3) / 4, 256, 0, stream>>>(lat, hyper_w, hyper_b, ws + OFF_HYP);
  prep_dynw_kernel<<<32, 256, 0, stream>>>(ws);
  prep_convw_kernel<<<144, 256, 0, stream>>>(res_w1, res_w2, img_w,
                                             (unsigned short*)(ws + OFF_CW1),
                                             (unsigned short*)(ws + OFF_CW2),
                                             ws + OFF_CWIMG);
  hipMemcpyAsync(ws + OFF_OUT, ca_init, (size_t)B_ * F_ * NPIX_ * sizeof(float),
                 hipMemcpyDeviceToDevice, stream);

  for (int st = 0; st < 16; ++st) {
    sobel_stats_kernel<<<1024, 256, 0, stream>>>(ws + OFF_OUT, sobu, ws + OFF_SRAW);
    mlp_mfma_kernel<<<1024, 256, 0, stream>>>(ws + OFF_OUT, sobu, ws, leak);
  }

  conv_mfma_kernel<<<1024, 256, 0, stream>>>(ws + OFF_OUT, (const unsigned short*)(ws + OFF_CW1),
                                             res_b1, (float*)(ws + OFF_TMP), 1);
  conv_mfma_kernel<<<1024, 256, 0, stream>>>((const float*)(ws + OFF_TMP),
                                             (const unsigned short*)(ws + OFF_CW2),
                                             res_b2, ws + OFF_OUT, 2);
  convimg_kernel<<<512, 256, 0, stream>>>(ws + OFF_OUT, ws + OFF_CWIMG, img_b, out);
}

// Round 8
// 932.301 us; speedup vs baseline: 2.1477x; 1.4254x over previous
//
#include <hip/hip_runtime.h>
#include <cstddef>

#define R_ 0.70710678118654752f
#define NEG_ 0.2f
#define EPS_ 1e-5f

constexpr int F_ = 64, C3_ = 192, HH_ = 128, NPIX_ = 16384, B_ = 4, LAT_ = 512, HYP_ = 33024;
// intra-row offsets inside one sample's hypernet output
constexpr int OFFI_WIN = 0, OFFI_BIN = 12288, OFFI_WMID = 12352, OFFI_BMID = 16448,
              OFFI_WOUT = 16512, OFFI_BOUT = 20608, OFFI_WSH = 20672, OFFI_BSH = 32960;
// workspace layout (float offsets)
constexpr size_t OFF_HYP = 0;         // 132096
constexpr size_t OFF_SRAW = 134144;   // 6144
constexpr size_t OFF_WFIN = 140288;   // 4*24576 ushort = 49152 floats (hi/lo frag pairs)
constexpr size_t OFF_WFSH = 189440;   // 49152
constexpr size_t OFF_WFMID = 238592;  // 4*8192 ushort = 16384 floats
constexpr size_t OFF_WFOUT = 254976;  // 16384
constexpr size_t OFF_CW1 = 271360;    // 73728 ushort = 36864 floats (conv1 frag pairs)
constexpr size_t OFF_CW2 = 308224;    // 36864
constexpr size_t OFF_CWIMG = 345088;  // 1728
constexpr size_t OFF_OUT = 346816;    // 4194304
constexpr size_t OFF_SOB = 4541120;   // 4*128*16384 packed-uint = 8388608 "floats"
constexpr size_t OFF_TMP = OFF_SOB;   // epilogue h (fp32, 4194304) aliases sob
// total = 12,929,728 floats = 51.7 MB

typedef short bf16x8 __attribute__((ext_vector_type(8)));
typedef float f32x4 __attribute__((ext_vector_type(4)));

// fp32 -> bf16 (RNE)
static __device__ __forceinline__ unsigned short f2b(float v) {
  unsigned u = __builtin_bit_cast(unsigned, v);
  u += 0x7fffu + ((u >> 16) & 1u);
  return (unsigned short)(u >> 16);
}
static __device__ __forceinline__ float b2f(unsigned short h) {
  return __builtin_bit_cast(float, ((unsigned)h) << 16);
}
static __device__ __forceinline__ void split2(float v, unsigned short& hi, unsigned short& lo) {
  hi = f2b(v);
  lo = f2b(v - b2f(hi));
}

// triple-MFMA split-bf16 product: acc += Ahi*Whi + Ahi*Wlo + Alo*Whi
#define MM3(acc, ahi, alo, whi, wlo)                                        \
  acc = __builtin_amdgcn_mfma_f32_16x16x32_bf16(ahi, whi, acc, 0, 0, 0);    \
  acc = __builtin_amdgcn_mfma_f32_16x16x32_bf16(ahi, wlo, acc, 0, 0, 0);    \
  acc = __builtin_amdgcn_mfma_f32_16x16x32_bf16(alo, whi, acc, 0, 0, 0);

// ---------------- hypernetwork GEMM ----------------------------------------------
__global__ __launch_bounds__(256) void hyper_gemm_kernel(
    const float* __restrict__ lat, const float* __restrict__ hw,
    const float* __restrict__ hb, float* __restrict__ hyp) {
  __shared__ float slat[B_ * LAT_];
  const int tid = threadIdx.x;
  for (int i = tid; i < B_ * LAT_; i += 256) slat[i] = lat[i];
  __syncthreads();
  const int wave = tid >> 6, lane = tid & 63;
  const int j = blockIdx.x * 4 + wave;
  if (j >= HYP_) return;
  const float* wr = hw + (size_t)j * LAT_;
  float a0 = 0.f, a1 = 0.f, a2 = 0.f, a3 = 0.f;
  for (int i = 0; i < LAT_; i += 64) {
    float w = wr[i + lane];
    a0 = __builtin_fmaf(w, slat[0 * LAT_ + i + lane], a0);
    a1 = __builtin_fmaf(w, slat[1 * LAT_ + i + lane], a1);
    a2 = __builtin_fmaf(w, slat[2 * LAT_ + i + lane], a2);
    a3 = __builtin_fmaf(w, slat[3 * LAT_ + i + lane], a3);
  }
  #pragma unroll
  for (int off = 32; off; off >>= 1) {
    a0 += __shfl_down(a0, off, 64);
    a1 += __shfl_down(a1, off, 64);
    a2 += __shfl_down(a2, off, 64);
    a3 += __shfl_down(a3, off, 64);
  }
  if (lane == 0) {
    float b = hb[j];
    hyp[0 * HYP_ + j] = a0 + b;
    hyp[1 * HYP_ + j] = a1 + b;
    hyp[2 * HYP_ + j] = a2 + b;
    hyp[3 * HYP_ + j] = a3 + b;
  }
}

// ---------------- dynamic weights -> STATIC split-bf16 frag layout (once) ---------
__global__ __launch_bounds__(256) void prep_dynw_kernel(float* wsm) {
  const int b = blockIdx.x >> 3, sl = blockIdx.x & 7;
  const int tid = threadIdx.x;
  const float* hyp = wsm + OFF_HYP + (size_t)b * HYP_;
  unsigned short* wfin = (unsigned short*)(wsm + OFF_WFIN) + (size_t)b * 24576;
  unsigned short* wfsh = (unsigned short*)(wsm + OFF_WFSH) + (size_t)b * 24576;
  unsigned short* wfmid = (unsigned short*)(wsm + OFF_WFMID) + (size_t)b * 8192;
  unsigned short* wfout = (unsigned short*)(wsm + OFF_WFOUT) + (size_t)b * 8192;

  if (sl < 6) {
    const int base = sl * 2048;
    for (int i = tid; i < 2048; i += 256) {
      int idx = base + i;
      int j = idx & 7, ch = (idx >> 3) & 63, g2 = (idx >> 9) & 3, ks = idx >> 11;
      int k = ks * 32 + g2 * 8 + j;
      int fbx = ((ks * 4 + g2) * 64 + ch) * 16;
      unsigned short h, l;
      split2(hyp[OFFI_WIN + ch * C3_ + k], h, l);
      wfin[fbx + j] = h; wfin[fbx + 8 + j] = l;
      split2(hyp[OFFI_WSH + ch * C3_ + k], h, l);
      wfsh[fbx + j] = h; wfsh[fbx + 8 + j] = l;
    }
  } else if (sl == 6) {
    for (int idx = tid; idx < 4096; idx += 256) {
      int j = idx & 7, ch = (idx >> 3) & 63, g2 = (idx >> 9) & 3, ks = idx >> 11;
      int k = ks * 32 + g2 * 8 + j;
      int fbx = ((ks * 4 + g2) * 64 + ch) * 16;
      unsigned short h, l;
      split2(hyp[OFFI_WMID + ch * 64 + k], h, l);
      wfmid[fbx + j] = h; wfmid[fbx + 8 + j] = l;
      split2(hyp[OFFI_WOUT + ch * 64 + k], h, l);
      wfout[fbx + j] = h; wfout[fbx + 8 + j] = l;
    }
  }
}

// ---------------- conv weights -> split-bf16 frag layout (+ img transpose) --------
__global__ __launch_bounds__(256) void prep_convw_kernel(
    const float* __restrict__ w1, const float* __restrict__ w2,
    const float* __restrict__ wi, unsigned short* __restrict__ wf1,
    unsigned short* __restrict__ wf2, float* __restrict__ wit) {
  const int idx = blockIdx.x * 256 + threadIdx.x;
  if (idx < 36864) {
    int j = idx & 7, ch = (idx >> 3) & 63, fg = idx >> 9;  // fg = ks*4+g
    int k = (fg >> 2) * 32 + (fg & 3) * 8 + j;
    int c = k & 63, t = k >> 6;
    int fb = (fg * 64 + ch) * 16;
    unsigned short h, l;
    split2(w1[(ch * 64 + c) * 9 + t], h, l);
    wf1[fb + j] = h; wf1[fb + 8 + j] = l;
    split2(w2[(ch * 64 + c) * 9 + t], h, l);
    wf2[fb + j] = h; wf2[fb + 8 + j] = l;
  }
  if (idx < 64 * 9 * 3) {
    int k = idx % 3, rest = idx / 3;
    int t = rest % 9, c = rest / 9;
    wit[idx] = wi[(k * 64 + c) * 9 + t];
  }
}

// ---------------- block reduction helper ------------------------------------------
__device__ __forceinline__ float blockReduceSum(float v, float* scratch) {
  const int tid = threadIdx.x;
  #pragma unroll
  for (int off = 32; off; off >>= 1) v += __shfl_down(v, off, 64);
  if ((tid & 63) == 0) scratch[tid >> 6] = v;
  __syncthreads();
  float r = scratch[0] + scratch[1] + scratch[2] + scratch[3];
  __syncthreads();
  return r;
}

__device__ __forceinline__ void hline_z(const float* __restrict__ P, int rr, int col,
                                        float& hdv, float& hsv, float& cv) {
  if (rr < 0 || rr > 127) { hdv = 0.f; hsv = 0.f; cv = 0.f; return; }
  const float* rp = P + rr * HH_;
  float vm2 = (col >= 2) ? rp[col - 2] : 0.f;
  float vm1 = (col >= 1) ? rp[col - 1] : 0.f;
  float v0 = rp[col];
  float vp1 = (col <= 126) ? rp[col + 1] : 0.f;
  float vp2 = (col <= 125) ? rp[col + 2] : 0.f;
  hdv = -vm2 - R_ * vm1 + R_ * vp1 + vp2;
  hsv = R_ * vm1 + v0 + R_ * vp1;
  cv = v0;
}

// ---------------- SinSobel -> packed split-bf16 gx/gy + raw IN partials -----------
__global__ __launch_bounds__(256) void sobel_stats_kernel(
    const float* __restrict__ outb, unsigned int* __restrict__ sob,
    float* __restrict__ sraw) {
  __shared__ float scr[4];
  const int bi = blockIdx.x;
  const int q = bi & 3, c = (bi >> 2) & 63, b = bi >> 8;
  const int tid = threadIdx.x;
  const int col = tid & 127;
  const int r0 = q * 32 + (tid >> 7) * 16;
  const float* P = outb + ((size_t)(b * F_ + c)) * NPIX_;
  unsigned int* ygx = sob + ((size_t)(b * 128 + 2 * c)) * NPIX_;
  unsigned int* ygy = ygx + NPIX_;

  float sI = 0.f, qI = 0.f, sX = 0.f, qX = 0.f, sY = 0.f, qY = 0.f;
  float hd_m1, hd_0, hd_p1, hs_m2, hs_m1, hs_0, hs_p1;
  float td, tc;
  hline_z(P, r0 - 2, col, td, hs_m2, tc);
  hline_z(P, r0 - 1, col, hd_m1, hs_m1, tc);
  hline_z(P, r0, col, hd_0, hs_0, tc);
  sI += tc; qI += tc * tc;
  hline_z(P, r0 + 1, col, hd_p1, hs_p1, tc);
  sI += tc; qI += tc * tc;

  for (int i = 0; i < 16; ++i) {
    const int r = r0 + i;
    const int nr = r + 2;
    float hd_new, hs_new, cnew;
    hline_z(P, nr, col, hd_new, hs_new, cnew);
    if (nr <= r0 + 15) { sI += cnew; qI += cnew * cnew; }
    float gxv = R_ * (hd_m1 + hd_p1) + hd_0;
    float gyv = -hs_m2 - R_ * hs_m1 + R_ * hs_p1 + hs_new;
    const int o = r * HH_ + col;
    unsigned short h, l;
    split2(gxv, h, l);
    ygx[o] = ((unsigned)h << 16) | l;
    split2(gyv, h, l);
    ygy[o] = ((unsigned)h << 16) | l;
    sX += gxv; qX += gxv * gxv;
    sY += gyv; qY += gyv * gyv;
    hd_m1 = hd_0; hd_0 = hd_p1; hd_p1 = hd_new;
    hs_m2 = hs_m1; hs_m1 = hs_0; hs_0 = hs_p1; hs_p1 = hs_new;
  }
  __syncthreads();
  float tI = blockReduceSum(sI, scr);
  float tQI = blockReduceSum(qI, scr);
  float tX = blockReduceSum(sX, scr);
  float tQX = blockReduceSum(qX, scr);
  float tY = blockReduceSum(sY, scr);
  float tQY = blockReduceSum(qY, scr);
  if (tid == 0) {
    float* r = sraw + (size_t)bi * 6;
    r[0] = tI; r[1] = tQI; r[2] = tX; r[3] = tQX; r[4] = tY; r[5] = tQY;
  }
}

// ---------------- MFMA dynamic MLP, split-bf16, wave-per-cg-slice -----------------
// block = (b, 64-px tile); 4 waves; wave w computes out-ch [w*16, w*16+16) for ALL
// 64 px (4 A-frags share each B-frag -> 4x fewer weight loads than wave-per-px).
__global__ __launch_bounds__(256, 2) void mlp_mfma_kernel(
    float* __restrict__ outb, const unsigned int* __restrict__ sobu,
    const float* __restrict__ wsf, const float* __restrict__ leak) {
  __shared__ unsigned short yhi[64 * 200];
  __shared__ unsigned short ylo[64 * 200];
  __shared__ unsigned short hhi[64 * 72];
  __shared__ unsigned short hlo[64 * 72];
  __shared__ float stl[C3_ * 2];
  const int bi = blockIdx.x;
  const int b = bi >> 8, t = bi & 255;
  const int px0 = t * 64;
  const int tid = threadIdx.x;

  // finalize InstanceNorm stats for this sample (64 threads x 3 channels each)
  if (tid < 64) {
    const int c = tid;
    const float* r = wsf + OFF_SRAW + ((size_t)(b * 64 + c) * 4) * 6;
    float sI = 0.f, qI = 0.f, sX = 0.f, qX = 0.f, sY = 0.f, qY = 0.f;
    #pragma unroll
    for (int q = 0; q < 4; ++q) {
      sI += r[q * 6 + 0]; qI += r[q * 6 + 1];
      sX += r[q * 6 + 2]; qX += r[q * 6 + 3];
      sY += r[q * 6 + 4]; qY += r[q * 6 + 5];
    }
    const float n = 1.f / 16384.f;
    float m;
    m = sI * n; stl[c * 2] = m;           stl[c * 2 + 1] = rsqrtf(qI * n - m * m + EPS_);
    const int cx = 64 + 2 * c, cy = cx + 1;
    m = sX * n; stl[cx * 2] = m;          stl[cx * 2 + 1] = rsqrtf(qX * n - m * m + EPS_);
    m = sY * n; stl[cy * 2] = m;          stl[cy * 2 + 1] = rsqrtf(qY * n - m * m + EPS_);
  }
  __syncthreads();

  const float* ob = outb + (size_t)b * F_ * NPIX_;
  const unsigned int* sbp = sobu + (size_t)b * 128 * NPIX_;
  #pragma unroll
  for (int it = 0; it < 12; ++it) {
    int ci = it * 256 + tid;
    int k = ci >> 4, pq = ci & 15;
    int kk = k ^ ((pq >> 1) << 3);
    unsigned short* ph = &yhi[(pq * 4) * 200 + kk];
    unsigned short* pl = &ylo[(pq * 4) * 200 + kk];
    const float mu = stl[k * 2], inv = stl[k * 2 + 1];
    float vv[4];
    if (k < 64) {
      float4 f = *(const float4*)(ob + (size_t)k * NPIX_ + px0 + pq * 4);
      vv[0] = f.x; vv[1] = f.y; vv[2] = f.z; vv[3] = f.w;
    } else {
      uint4 v = *(const uint4*)(sbp + (size_t)(k - 64) * NPIX_ + px0 + pq * 4);
      vv[0] = b2f((unsigned short)(v.x >> 16)) + b2f((unsigned short)(v.x & 0xffff));
      vv[1] = b2f((unsigned short)(v.y >> 16)) + b2f((unsigned short)(v.y & 0xffff));
      vv[2] = b2f((unsigned short)(v.z >> 16)) + b2f((unsigned short)(v.z & 0xffff));
      vv[3] = b2f((unsigned short)(v.w >> 16)) + b2f((unsigned short)(v.w & 0xffff));
    }
    #pragma unroll
    for (int e = 0; e < 4; ++e) {
      unsigned short h, l;
      split2((vv[e] - mu) * inv, h, l);
      ph[e * 200] = h; pl[e * 200] = l;
    }
  }
  __syncthreads();

  const int wave = tid >> 6, lane = tid & 63;
  const int lrow = lane & 15, g = lane >> 4;
  const int chm = wave * 16 + lrow;  // this wave's output-channel for this lane
  const float lf = fminf(fmaxf(leak[0], 0.001f), 1000.f);
  const float* hyp = wsf + OFF_HYP + (size_t)b * HYP_;
  const unsigned short* wfin = (const unsigned short*)(wsf + OFF_WFIN) + (size_t)b * 24576;
  const unsigned short* wfsh = (const unsigned short*)(wsf + OFF_WFSH) + (size_t)b * 24576;
  const unsigned short* wfmid = (const unsigned short*)(wsf + OFF_WFMID) + (size_t)b * 8192;
  const unsigned short* wfout = (const unsigned short*)(wsf + OFF_WFOUT) + (size_t)b * 8192;

  // ---- phase 1: h1 + shortcut (K = 192), B-frag shared across 4 px-frags ----
  f32x4 aH[4], aS[4];
  {
    float b1 = hyp[OFFI_BIN + chm], b2 = hyp[OFFI_BSH + chm];
    #pragma unroll
    for (int pf = 0; pf < 4; ++pf) {
      aH[pf] = (f32x4){b1, b1, b1, b1};
      aS[pf] = (f32x4){b2, b2, b2, b2};
    }
  }
  #pragma unroll
  for (int ks = 0; ks < 6; ++ks) {
    const size_t wo = (size_t)((ks * 4 + g) * 64 + chm) * 16;
    bf16x8 whiI = *(const bf16x8*)(wfin + wo);
    bf16x8 wloI = *(const bf16x8*)(wfin + wo + 8);
    bf16x8 whiS = *(const bf16x8*)(wfsh + wo);
    bf16x8 wloS = *(const bf16x8*)(wfsh + wo + 8);
    #pragma unroll
    for (int pf = 0; pf < 4; ++pf) {
      const int pxl = pf * 16 + lrow;
      const int kb = pxl * 200 + ((ks * 32 + g * 8) ^ ((pxl >> 3) << 3));
      bf16x8 ahi = *(const bf16x8*)&yhi[kb];
      bf16x8 alo = *(const bf16x8*)&ylo[kb];
      MM3(aH[pf], ahi, alo, whiI, wloI);
      MM3(aS[pf], ahi, alo, whiS, wloS);
    }
  }
  // lrelu(h1) -> htile: px = pf*16 + g*4 + j, ch = chm
  #pragma unroll
  for (int pf = 0; pf < 4; ++pf) {
    #pragma unroll
    for (int j = 0; j < 4; ++j) {
      float v = aH[pf][j];
      v = (v >= 0.f) ? v : NEG_ * v;
      unsigned short h, l;
      split2(v, h, l);
      const int o = (pf * 16 + g * 4 + j) * 72 + chm;
      hhi[o] = h; hlo[o] = l;
    }
  }
  __syncthreads();
  // ---- phase 2: h2 (K = 64) ----
  f32x4 aM[4];
  {
    float bm = hyp[OFFI_BMID + chm];
    #pragma unroll
    for (int pf = 0; pf < 4; ++pf) aM[pf] = (f32x4){bm, bm, bm, bm};
  }
  #pragma unroll
  for (int ks = 0; ks < 2; ++ks) {
    const size_t wo = (size_t)((ks * 4 + g) * 64 + chm) * 16;
    bf16x8 whi = *(const bf16x8*)(wfmid + wo);
    bf16x8 wlo = *(const bf16x8*)(wfmid + wo + 8);
    #pragma unroll
    for (int pf = 0; pf < 4; ++pf) {
      const int kb = (pf * 16 + lrow) * 72 + ks * 32 + g * 8;
      bf16x8 ahi = *(const bf16x8*)&hhi[kb];
      bf16x8 alo = *(const bf16x8*)&hlo[kb];
      MM3(aM[pf], ahi, alo, whi, wlo);
    }
  }
  __syncthreads();
  #pragma unroll
  for (int pf = 0; pf < 4; ++pf) {
    #pragma unroll
    for (int j = 0; j < 4; ++j) {
      float v = aM[pf][j];
      v = (v >= 0.f) ? v : NEG_ * v;
      unsigned short h, l;
      split2(v, h, l);
      const int o = (pf * 16 + g * 4 + j) * 72 + chm;
      hhi[o] = h; hlo[o] = l;
    }
  }
  __syncthreads();
  // ---- phase 3: h3 (K = 64) ----
  f32x4 aO[4];
  {
    float bo = hyp[OFFI_BOUT + chm];
    #pragma unroll
    for (int pf = 0; pf < 4; ++pf) aO[pf] = (f32x4){bo, bo, bo, bo};
  }
  #pragma unroll
  for (int ks = 0; ks < 2; ++ks) {
    const size_t wo = (size_t)((ks * 4 + g) * 64 + chm) * 16;
    bf16x8 whi = *(const bf16x8*)(wfout + wo);
    bf16x8 wlo = *(const bf16x8*)(wfout + wo + 8);
    #pragma unroll
    for (int pf = 0; pf < 4; ++pf) {
      const int kb = (pf * 16 + lrow) * 72 + ks * 32 + g * 8;
      bf16x8 ahi = *(const bf16x8*)&hhi[kb];
      bf16x8 alo = *(const bf16x8*)&hlo[kb];
      MM3(aO[pf], ahi, alo, whi, wlo);
    }
  }
  // ---- out += lf * (h3 + shortcut): ch = chm, px = px0 + pf*16 + g*4 + j ----
  #pragma unroll
  for (int pf = 0; pf < 4; ++pf) {
    float* op = outb + ((size_t)(b * F_ + chm)) * NPIX_ + px0 + pf * 16 + g * 4;
    f32x4 cur = *(f32x4*)op;
    #pragma unroll
    for (int j = 0; j < 4; ++j) cur[j] += lf * (aO[pf][j] + aS[pf][j]);
    *(f32x4*)op = cur;
  }
}

// ---------------- MFMA 3x3 conv (implicit GEMM, split-bf16) -----------------------
// swizzle f(i,rowp) = ((i>>2)&7) ^ ((i&3)<<1) ^ rowp : bijective on i mod 8 (reads
// conflict-free) AND spreads quad-stepped staging writes across 8 bank groups.
__global__ __launch_bounds__(256, 2) void conv_mfma_kernel(
    const float* __restrict__ in, const unsigned short* __restrict__ wf,
    const float* __restrict__ bias, float* __restrict__ dst, int mode) {
  __shared__ unsigned short ahi[3 * 72 * 64];
  __shared__ unsigned short alo[3 * 72 * 64];
  const int bi = blockIdx.x;
  const int b = bi >> 8, tile = bi & 255;
  const int row = tile >> 1, colbase = (tile & 1) << 6;
  const int tid = threadIdx.x;
  const float* ip = in + (size_t)b * F_ * NPIX_;

  for (int idx = tid; idx < 3456; idx += 256) {
    const int chunk = idx % 18;
    const int rowp = (idx / 18) % 3;
    const int ch = idx / 54;
    const int r2 = row - 1 + rowp;
    const int gcol0 = colbase - 4 + chunk * 4;
    float4 v;
    if (r2 < 0 || r2 > 127) {
      v = make_float4(0.f, 0.f, 0.f, 0.f);
    } else if (gcol0 >= 0 && gcol0 <= 124) {
      v = *(const float4*)(ip + (size_t)ch * NPIX_ + r2 * HH_ + gcol0);
    } else {
      const float* rp = ip + (size_t)ch * NPIX_ + r2 * HH_;
      v.x = (gcol0 >= 0 && gcol0 < 128) ? rp[gcol0] : 0.f;
      v.y = (gcol0 + 1 >= 0 && gcol0 + 1 < 128) ? rp[gcol0 + 1] : 0.f;
      v.z = (gcol0 + 2 >= 0 && gcol0 + 2 < 128) ? rp[gcol0 + 2] : 0.f;
      v.w = (gcol0 + 3 >= 0 && gcol0 + 3 < 128) ? rp[gcol0 + 3] : 0.f;
    }
    const float vv[4] = {v.x, v.y, v.z, v.w};
    #pragma unroll
    for (int e = 0; e < 4; ++e) {
      const int i = chunk * 4 + e;
      const int sw = (((i >> 2) & 7) ^ ((i & 3) << 1) ^ rowp) << 3;
      const int a = (rowp * 72 + i) * 64 + (ch ^ sw);
      unsigned short h, l;
      split2(vv[e], h, l);
      ahi[a] = h; alo[a] = l;
    }
  }
  __syncthreads();

  const int wave = tid >> 6, lane = tid & 63;
  const int lrow = lane & 15, g = lane >> 4;
  const int pxl = wave * 16 + lrow;
  f32x4 acc[4];
  #pragma unroll
  for (int cg = 0; cg < 4; ++cg) {
    float bz = bias[cg * 16 + lrow];
    acc[cg] = (f32x4){bz, bz, bz, bz};
  }
  for (int ks = 0; ks < 18; ++ks) {
    const int kbase = ks * 32 + g * 8;
    const int t = kbase >> 6, c0 = kbase & 63;
    const int dy = t / 3 - 1, dx = t % 3 - 1;
    const int rowp = 1 + dy;
    const int i = pxl + 4 + dx;
    const int sw = (((i >> 2) & 7) ^ ((i & 3) << 1) ^ rowp) << 3;
    const int a = (rowp * 72 + i) * 64 + (c0 ^ sw);
    bf16x8 a_hi = *(const bf16x8*)&ahi[a];
    bf16x8 a_lo = *(const bf16x8*)&alo[a];
    #pragma unroll
    for (int cg = 0; cg < 4; ++cg) {
      const unsigned short* wp = wf + (size_t)((ks * 4 + g) * 64 + cg * 16 + lrow) * 16;
      bf16x8 whi = *(const bf16x8*)wp;
      bf16x8 wlo = *(const bf16x8*)(wp + 8);
      MM3(acc[cg], a_hi, a_lo, whi, wlo);
    }
  }
  #pragma unroll
  for (int cg = 0; cg < 4; ++cg) {
    float* op = dst + ((size_t)(b * F_ + cg * 16 + lrow)) * NPIX_ + row * HH_ + colbase +
                wave * 16 + g * 4;
    if (mode == 1) {
      f32x4 r;
      #pragma unroll
      for (int j = 0; j < 4; ++j) {
        float v = acc[cg][j];
        r[j] = (v >= 0.f) ? v : NEG_ * v;
      }
      *(f32x4*)op = r;
    } else {
      f32x4 cur = *(f32x4*)op;
      #pragma unroll
      for (int j = 0; j < 4; ++j) cur[j] += acc[cg][j];
      *(f32x4*)op = cur;
    }
  }
}

// ---------------- final image conv (3 outputs, VALU) ------------------------------
__global__ __launch_bounds__(256, 4) void convimg_kernel(
    const float* __restrict__ outb, const float* __restrict__ wT,
    const float* __restrict__ bias, float* __restrict__ img) {
  __shared__ float part[2 * 128 * 3];
  const int bi = blockIdx.x;
  const int b = bi >> 7, pxb = bi & 127;
  const int tid = threadIdx.x;
  const int px = tid & 127;
  const int hf = __builtin_amdgcn_readfirstlane(tid >> 7);
  const int p = pxb * 128 + px;
  const int row = p >> 7, col = p & 127;
  float a0 = 0.f, a1 = 0.f, a2 = 0.f;
  const float* ip = outb + (size_t)b * F_ * NPIX_;
  for (int cc = 0; cc < 32; ++cc) {
    const int c = hf * 32 + cc;
    const float* pl = ip + (size_t)c * NPIX_;
    #pragma unroll
    for (int t = 0; t < 9; ++t) {
      const int dy = t / 3 - 1, dx = t % 3 - 1;
      const int r2 = row + dy, c2 = col + dx;
      float v = (r2 >= 0 && r2 < 128 && c2 >= 0 && c2 < 128) ? pl[r2 * HH_ + c2] : 0.f;
      const float* wp = wT + (c * 9 + t) * 3;
      a0 = __builtin_fmaf(v, wp[0], a0);
      a1 = __builtin_fmaf(v, wp[1], a1);
      a2 = __builtin_fmaf(v, wp[2], a2);
    }
  }
  part[(hf * 128 + px) * 3 + 0] = a0;
  part[(hf * 128 + px) * 3 + 1] = a1;
  part[(hf * 128 + px) * 3 + 2] = a2;
  __syncthreads();
  if (hf == 0) {
    float r0 = a0 + part[(128 + px) * 3 + 0] + bias[0];
    float r1 = a1 + part[(128 + px) * 3 + 1] + bias[1];
    float r2 = a2 + part[(128 + px) * 3 + 2] + bias[2];
    img[((size_t)b * 3 + 0) * NPIX_ + p] = fminf(fmaxf(r0, -1.f), 1.f);
    img[((size_t)b * 3 + 1) * NPIX_ + p] = fminf(fmaxf(r1, -1.f), 1.f);
    img[((size_t)b * 3 + 2) * NPIX_ + p] = fminf(fmaxf(r2, -1.f), 1.f);
  }
}

extern "C" void kernel_launch(void* const* d_in, const int* in_sizes, int n_in,
                              void* d_out, int out_size, void* d_ws, size_t ws_size,
                              hipStream_t stream) {
  const float* lat = (const float*)d_in[0];
  const float* ca_init = (const float*)d_in[1];
  const float* leak = (const float*)d_in[2];
  const float* hyper_w = (const float*)d_in[3];
  const float* hyper_b = (const float*)d_in[4];
  const float* res_w1 = (const float*)d_in[5];
  const float* res_b1 = (const float*)d_in[6];
  const float* res_w2 = (const float*)d_in[7];
  const float* res_b2 = (const float*)d_in[8];
  const float* img_w = (const float*)d_in[9];
  const float* img_b = (const float*)d_in[10];
  float* out = (float*)d_out;
  float* ws = (float*)d_ws;
  unsigned int* sobu = (unsigned int*)(ws + OFF_SOB);

  hyper_gemm_kernel<<<(HYP_ + 3) / 4, 256, 0, stream>>>(lat, hyper_w, hyper_b, ws + OFF_HYP);
  prep_dynw_kernel<<<32, 256, 0, stream>>>(ws);
  prep_convw_kernel<<<144, 256, 0, stream>>>(res_w1, res_w2, img_w,
                                             (unsigned short*)(ws + OFF_CW1),
                                             (unsigned short*)(ws + OFF_CW2),
                                             ws + OFF_CWIMG);
  hipMemcpyAsync(ws + OFF_OUT, ca_init, (size_t)B_ * F_ * NPIX_ * sizeof(float),
                 hipMemcpyDeviceToDevice, stream);

  for (int st = 0; st < 16; ++st) {
    sobel_stats_kernel<<<1024, 256, 0, stream>>>(ws + OFF_OUT, sobu, ws + OFF_SRAW);
    mlp_mfma_kernel<<<1024, 256, 0, stream>>>(ws + OFF_OUT, sobu, ws, leak);
  }

  conv_mfma_kernel<<<1024, 256, 0, stream>>>(ws + OFF_OUT, (const unsigned short*)(ws + OFF_CW1),
                                             res_b1, (float*)(ws + OFF_TMP), 1);
  conv_mfma_kernel<<<1024, 256, 0, stream>>>((const float*)(ws + OFF_TMP),
                                             (const unsigned short*)(ws + OFF_CW2),
                                             res_b2, ws + OFF_OUT, 2);
  convimg_kernel<<<512, 256, 0, stream>>>(ws + OFF_OUT, ws + OFF_CWIMG, img_b, out);
}